// Round 5
// baseline (7901.795 us; speedup 1.0000x reference)
//
#include <hip/hip_runtime.h>
#include <cstddef>
#include <cstdint>

typedef unsigned short u16;
typedef __attribute__((ext_vector_type(8))) unsigned short u16x8;
typedef __attribute__((ext_vector_type(8))) short s16x8;
typedef __attribute__((ext_vector_type(4))) float f32x4;

#define B_ 8
#define T_ 256
#define U_ 64
#define D_ 512
#define G_ 2048   // 4*DUNITS
#define OD 500
#define NB 64     // persistent scan blocks (<=256 -> co-residency guaranteed)

__device__ __forceinline__ float bf2f(u16 u){ unsigned v=((unsigned)u)<<16; return __builtin_bit_cast(float,v); }
__device__ __forceinline__ u16 f2bf(float f){ unsigned u=__builtin_bit_cast(unsigned,f); u += 0x7fffu + ((u>>16)&1u); return (u16)(u>>16); }
__device__ __forceinline__ float sigm(float x){ return 1.f/(1.f+expf(-x)); }
__device__ __forceinline__ float wredsum(float v){
  #pragma unroll
  for(int o=32;o;o>>=1) v += __shfl_xor(v,o);
  return v;
}
__device__ __forceinline__ float wredmax(float v){
  #pragma unroll
  for(int o=32;o;o>>=1) v = fmaxf(v,__shfl_xor(v,o));
  return v;
}

// monotonic grid barrier: all NB blocks arrive, spin until cnt reaches NB*gen.
// agent-scope acq_rel atomics + threadfence handle cross-XCD L2 visibility.
__device__ __forceinline__ void gridbar(unsigned* cnt, unsigned target){
  __syncthreads();
  if(threadIdx.x==0){
    __threadfence();   // release: wb this XCD's L2 (stores from whole block are in L2: L1 is write-through, syncthreads drained vmcnt)
    __hip_atomic_fetch_add(cnt,1u,__ATOMIC_ACQ_REL,__HIP_MEMORY_SCOPE_AGENT);
    while(__hip_atomic_load(cnt,__ATOMIC_ACQUIRE,__HIP_MEMORY_SCOPE_AGENT) < target){
      __builtin_amdgcn_s_sleep(1);
    }
    __threadfence();   // acquire: invalidate L1/L2 so fresh producer data is fetched
  }
  __syncthreads();
}

// ---------------- conversion kernels (one-time per call) ----------------
__global__ void k_f2bf(const float* __restrict__ s, u16* __restrict__ d, int n){
  int i=blockIdx.x*256+threadIdx.x; if(i<n) d[i]=f2bf(s[i]);
}
// d[c*R + r] = s[r*C + c]
__global__ void k_trans_bf(const float* __restrict__ s, u16* __restrict__ d, int R, int C){
  int i=blockIdx.x*256+threadIdx.x; if(i>=R*C) return;
  int c=i/R, r=i-c*R; d[i]=f2bf(s[(size_t)r*C+c]);
}
// att slice of W_ih0: d[g*512+e] = W_ih0[g*1024 + 512 + e]
__global__ void k_wi0a(const float* __restrict__ W, u16* __restrict__ d){
  int i=blockIdx.x*256+threadIdx.x; if(i>=G_*D_) return;
  int g=i>>9, e=i&511; d[i]=f2bf(W[(size_t)g*1024 + 512 + e]);
}
// WoT[o][j] = W_out[j][o], o padded to 512 with zeros
__global__ void k_woT(const float* __restrict__ W, u16* __restrict__ d){
  int i=blockIdx.x*256+threadIdx.x; if(i>=512*512) return;
  int o=i>>9, j=i&511; d[i] = (o<OD)? f2bf(W[(size_t)j*OD+o]) : (u16)0;
}

// ---------------- generic bf16-MFMA GEMM ----------------
// C[M,N] = act( A[M,K] @ B + bias1 + bias2 ), tiles 64x64, K%32==0, M%64==0, N%64==0.
// bT=0: B[k*ldb+n]; bT=1: B[n*ldb+k]. gidx: optional row gather for A.
__global__ __launch_bounds__(256) void k_gemm(
  const float* __restrict__ A, const int* __restrict__ gidx, int lda,
  const float* __restrict__ Bm, int ldb, int bT,
  const float* __restrict__ bias1, const float* __restrict__ bias2,
  int actTanh, int outBf16, void* __restrict__ C, int ldc, int K)
{
  __shared__ __align__(16) u16 As[64][40];
  __shared__ __align__(16) u16 Bs[64][40];
  int tid=threadIdx.x;
  int m0=blockIdx.x*64, n0=blockIdx.y*64;
  int w=tid>>6, l=tid&63;
  f32x4 acc[4];
  #pragma unroll
  for(int nt=0;nt<4;++nt) acc[nt]=(f32x4){0.f,0.f,0.f,0.f};
  int arow=tid>>2, aseg=tid&3;
  int ar = gidx ? gidx[m0+arow] : (m0+arow);
  const float* Ap = A + (size_t)ar*lda + aseg*8;

  for(int kt=0;kt<K/32;++kt){
    const float* ap = Ap + kt*32;
    f32x4 a0=*(const f32x4*)ap, a1=*(const f32x4*)(ap+4);
    #pragma unroll
    for(int i=0;i<4;++i){ As[arow][aseg*8+i]=f2bf(a0[i]); As[arow][aseg*8+4+i]=f2bf(a1[i]); }
    if(bT){
      const float* bp = Bm + (size_t)(n0+arow)*ldb + kt*32 + aseg*8;
      f32x4 b0=*(const f32x4*)bp, b1=*(const f32x4*)(bp+4);
      #pragma unroll
      for(int i=0;i<4;++i){ Bs[arow][aseg*8+i]=f2bf(b0[i]); Bs[arow][aseg*8+4+i]=f2bf(b1[i]); }
    } else {
      int bk=tid>>3, bn=(tid&7)*8;
      const float* bp = Bm + (size_t)(kt*32+bk)*ldb + n0 + bn;
      f32x4 b0=*(const f32x4*)bp, b1=*(const f32x4*)(bp+4);
      #pragma unroll
      for(int i=0;i<4;++i){ Bs[bn+i][bk]=f2bf(b0[i]); Bs[bn+4+i][bk]=f2bf(b1[i]); }
    }
    __syncthreads();
    s16x8 af = *(const s16x8*)&As[w*16 + (l&15)][(l>>4)*8];
    #pragma unroll
    for(int nt=0;nt<4;++nt){
      s16x8 bf = *(const s16x8*)&Bs[nt*16 + (l&15)][(l>>4)*8];
      acc[nt]=__builtin_amdgcn_mfma_f32_16x16x32_bf16(af,bf,acc[nt],0,0,0);
    }
    __syncthreads();
  }
  int mr = w*16 + ((l>>4)<<2), cc = l&15;
  #pragma unroll
  for(int nt=0;nt<4;++nt){
    int gn = n0 + nt*16 + cc;
    float bb = (bias1?bias1[gn]:0.f) + (bias2?bias2[gn]:0.f);
    #pragma unroll
    for(int r=0;r<4;++r){
      int gm = m0 + mr + r;
      float v = acc[nt][r] + bb;
      if(actTanh) v = tanhf(v);
      if(outBf16) ((u16*)C)[(size_t)gm*ldc+gn] = f2bf(v);
      else        ((float*)C)[(size_t)gm*ldc+gn] = v;
    }
  }
}

// ---------------- persistent scan kernel ----------------
// 64 blocks x 256 threads, 3 grid barriers per step.
// Per step u:
//   P1: stage h0,h1prev to LDS; D = LSTM1 gates for step u-1 (all threads);
//       q_u = tanh(h0 @ Wd + b) (threads 0..63, 64 outputs/block); epilogue h1/c1 + hdec.
//   P2: blocks 0..7: attention for batch b=bid; blocks 8..63: gpart = h0 @ Whh0^T.
//   P3: gates0 = ey_pre[u] + gpart + attc @ Wia^T; epilogue h0/c0.
// Block bid owns j in [bid*8, bid*8+8) -> its 32 gate-rows stay hot in its XCD L2.
__global__ __launch_bounds__(256) void k_scan(
  const u16* __restrict__ WdT, const float* __restrict__ b_att_dec,
  const u16* __restrict__ pe_bf, const u16* __restrict__ hs_bf, const int* __restrict__ hlens,
  const u16* __restrict__ Wi0a, const u16* __restrict__ Whh0b,
  const u16* __restrict__ Wih1b, const u16* __restrict__ Whh1b,
  const float* __restrict__ b_ih1, const float* __restrict__ b_hh1,
  const float* __restrict__ ey_pre,
  float* __restrict__ q_g, float* __restrict__ attc, float* __restrict__ gpart,
  float* __restrict__ h0g, float* __restrict__ h1g,  // h1g: 2 buffers of 4096
  float* __restrict__ c0g, float* __restrict__ c1g,
  float* __restrict__ hdec, unsigned* __restrict__ barcnt)
{
  __shared__ float sm[2*8*516 + 512];
  int tid=threadIdx.x, bid=blockIdx.x;
  unsigned baridx=0;
  float* xs=sm; float* hs=sm+8*516; float* gl=sm+2*8*516;

  for(int u=0; u<=U_; ++u){
    // ---------- P1 ----------
    const float* h1prev = h1g + (u&1)*4096;        // h1_{u-2}
    float*       h1new  = h1g + ((u+1)&1)*4096;    // h1_{u-1}
    for(int i=tid;i<4096;i+=256){ int b=i>>9,k=i&511; xs[b*516+k]=h0g[i]; hs[b*516+k]=h1prev[i]; }
    __syncthreads();
    if(u>0){
      int b=tid&7, g=(tid>>3)&3, jj=tid>>5;
      int row=g*512 + bid*8 + jj;
      float a=b_ih1[row]+b_hh1[row];
      const u16* w1=Wih1b+(size_t)row*512;
      const u16* w2=Whh1b+(size_t)row*512;
      for(int kc=0;kc<64;++kc){
        u16x8 x1=*(const u16x8*)(w1+kc*8);
        u16x8 x2=*(const u16x8*)(w2+kc*8);
        #pragma unroll
        for(int i=0;i<8;++i) a += bf2f(x1[i])*xs[b*516+kc*8+i] + bf2f(x2[i])*hs[b*516+kc*8+i];
      }
      gl[jj*32+g*8+b]=a;
    }
    if(u<U_ && tid<64){
      int idx=bid*64+tid, b=idx>>9, a_=idx&511;
      const u16* wr=WdT+(size_t)a_*512;
      float acc=0.f;
      for(int kc=0;kc<64;++kc){
        u16x8 v=*(const u16x8*)(wr+kc*8);
        #pragma unroll
        for(int i=0;i<8;++i) acc += bf2f(v[i])*xs[b*516+kc*8+i];
      }
      q_g[idx]=tanhf(acc+b_att_dec[a_]);
    }
    __syncthreads();
    if(u>0 && tid<64){
      int b=tid&7, jj=tid>>3, j=bid*8+jj;
      float i_=sigm(gl[jj*32+0*8+b]), f_=sigm(gl[jj*32+1*8+b]);
      float g_=tanhf(gl[jj*32+2*8+b]), o_=sigm(gl[jj*32+3*8+b]);
      float c=f_*c1g[b*512+j]+i_*g_;
      float h=o_*tanhf(c);
      c1g[b*512+j]=c; h1new[b*512+j]=h;
      hdec[((size_t)(b*64+(u-1)))*512 + j]=h;
    }
    if(u==U_) break;                 // final D done; all blocks exit together
    gridbar(barcnt, NB*(++baridx));

    // ---------- P2 ----------
    if(bid<8){
      int b=bid;
      float* qs=sm; float* ew=sm+512; float* red=sm+512+256;   // overwrites xs (unused by bid<8 from here)
      for(int i=tid;i<512;i+=256) qs[i]=q_g[b*512+i];
      __syncthreads();
      int wv=tid>>6, ln=tid&63, hl=hlens[b];
      for(int t=wv;t<256;t+=4){
        const u16* p = pe_bf + ((size_t)(b*256+t))*512 + ln*8;
        u16x8 v=*(const u16x8*)p;
        float a=0.f;
        #pragma unroll
        for(int i=0;i<8;++i) a += bf2f(v[i])*qs[ln*8+i];
        a=wredsum(a);
        if(ln==0) ew[t]=(t<hl)? a : -1e30f;
      }
      __syncthreads();
      float val=ew[tid];
      float m=wredmax(val);
      if(ln==0) red[wv]=m;
      __syncthreads();
      float M=fmaxf(fmaxf(red[0],red[1]),fmaxf(red[2],red[3]));
      float p=expf(val-M);
      float s=wredsum(p);
      if(ln==0) red[4+wv]=s;
      __syncthreads();
      float S=red[4]+red[5]+red[6]+red[7];
      ew[tid]=p/S;
      __syncthreads();
      for(int d=tid;d<512;d+=256){
        const u16* hp=hs_bf+(size_t)b*256*512+d;
        float a=0.f;
        for(int t=0;t<256;++t) a+=ew[t]*bf2f(hp[(size_t)t*512]);
        attc[b*512+d]=a;
      }
    } else {
      // gpart[row*8+b] = h0 . Whh0[row]  (xs still holds h0 for blocks >=8)
      for(int idx=(bid-8)*256+tid; idx<16384; idx+=56*256){
        int b=idx&7, row=idx>>3;
        const u16* w=Whh0b+(size_t)row*512;
        float a=0.f;
        for(int kc=0;kc<64;++kc){
          u16x8 x=*(const u16x8*)(w+kc*8);
          #pragma unroll
          for(int i=0;i<8;++i) a += bf2f(x[i])*xs[b*516+kc*8+i];
        }
        gpart[(size_t)row*8+b]=a;
      }
    }
    gridbar(barcnt, NB*(++baridx));

    // ---------- P3 ----------
    for(int i=tid;i<4096;i+=256){ int b=i>>9,k=i&511; xs[b*516+k]=attc[i]; }
    __syncthreads();
    {
      int b=tid&7, g=(tid>>3)&3, jj=tid>>5;
      int row=g*512 + bid*8 + jj;
      float a=ey_pre[((size_t)((b<<6)|u))*2048 + row] + gpart[(size_t)row*8+b];
      const u16* w=Wi0a+(size_t)row*512;
      for(int kc=0;kc<64;++kc){
        u16x8 x=*(const u16x8*)(w+kc*8);
        #pragma unroll
        for(int i=0;i<8;++i) a += bf2f(x[i])*xs[b*516+kc*8+i];
      }
      gl[jj*32+g*8+b]=a;
    }
    __syncthreads();
    if(tid<64){
      int b=tid&7, jj=tid>>3, j=bid*8+jj;
      float i_=sigm(gl[jj*32+0*8+b]), f_=sigm(gl[jj*32+1*8+b]);
      float g_=tanhf(gl[jj*32+2*8+b]), o_=sigm(gl[jj*32+3*8+b]);
      float c=f_*c0g[b*512+j]+i_*g_;
      c0g[b*512+j]=c;
      h0g[b*512+j]=o_*tanhf(c);
    }
    gridbar(barcnt, NB*(++baridx));
  }
}

// ---------------- joint network ----------------
// out[b,t,u,o] = tanh(lin_enc[b,t,:]+lin_dec[b,u,:]) @ W_out + b_out
__global__ __launch_bounds__(256) void k_joint(
  const float* __restrict__ lin_enc, const float* __restrict__ lin_dec,
  const u16* __restrict__ WoT, const float* __restrict__ b_out,
  float* __restrict__ out)
{
  __shared__ __align__(16) u16 As[64*512];
  __shared__ float ld_s[512];
  int tid=threadIdx.x, bid=blockIdx.x;
  int b=bid>>8, u=(bid>>2)&63, t0=(bid&3)*64;
  for(int i=tid;i<512;i+=256) ld_s[i]=lin_dec[((size_t)((b<<6)|u))*512 + i];
  __syncthreads();
  const float* le = lin_enc + ((size_t)(b*256 + t0))*512;
  for(int it=0;it<16;++it){
    int idx=it*256+tid;
    int row=idx>>6, c0=(idx&63)*8;
    f32x4 x0=*(const f32x4*)(le + (size_t)row*512 + c0);
    f32x4 x1=*(const f32x4*)(le + (size_t)row*512 + c0 + 4);
    u16x8 pk;
    #pragma unroll
    for(int i=0;i<4;++i){
      pk[i]  =f2bf(tanhf(x0[i]+ld_s[c0+i]));
      pk[4+i]=f2bf(tanhf(x1[i]+ld_s[c0+4+i]));
    }
    int sc = c0 ^ ((row&7)<<3);
    *(u16x8*)&As[row*512+sc]=pk;
  }
  __syncthreads();
  int w=tid>>6, l=tid&63;
  for(int ch=0;ch<8;++ch){
    int n0=ch*64 + w*16;
    int o = n0 + (l&15);
    s16x8 bfr[16];
    const u16* wp = WoT + (size_t)o*512 + ((l>>4)*8);
    #pragma unroll
    for(int ks=0;ks<16;++ks) bfr[ks]=*(const s16x8*)(wp + ks*32);
    float bo = (o<OD)? b_out[o] : 0.f;
    for(int mt=0;mt<4;++mt){
      f32x4 acc=(f32x4){0.f,0.f,0.f,0.f};
      int row = mt*16 + (l&15);
      int sw  = (row&7)<<3;
      #pragma unroll
      for(int ks=0;ks<16;++ks){
        int cidx=(ks*32 + (l>>4)*8) ^ sw;
        s16x8 af=*(const s16x8*)&As[row*512+cidx];
        acc=__builtin_amdgcn_mfma_f32_16x16x32_bf16(af,bfr[ks],acc,0,0,0);
      }
      if(o<OD){
        #pragma unroll
        for(int r=0;r<4;++r){
          int t = t0 + mt*16 + ((l>>4)<<2) + r;
          out[(((size_t)(b*256+t))*64 + u)*500 + o] = acc[r] + bo;
        }
      }
    }
  }
}

// ---------------- host launcher ----------------
extern "C" void kernel_launch(void* const* d_in, const int* in_sizes, int n_in,
                              void* d_out, int out_size, void* d_ws, size_t ws_size,
                              hipStream_t stream)
{
  (void)in_sizes; (void)n_in; (void)out_size; (void)ws_size;
  const float* hs_pad   =(const float*)d_in[0];
  const int*   ys       =(const int*)  d_in[1];
  const int*   hlens    =(const int*)  d_in[2];
  const float* emb      =(const float*)d_in[3];
  const float* W_ih0    =(const float*)d_in[4];
  const float* W_hh0    =(const float*)d_in[5];
  const float* b_ih0    =(const float*)d_in[6];
  const float* b_hh0    =(const float*)d_in[7];
  const float* W_ih1    =(const float*)d_in[8];
  const float* W_hh1    =(const float*)d_in[9];
  const float* b_ih1    =(const float*)d_in[10];
  const float* b_hh1    =(const float*)d_in[11];
  const float* W_att_enc=(const float*)d_in[12];
  const float* b_att_enc=(const float*)d_in[13];
  const float* W_att_dec=(const float*)d_in[14];
  const float* b_att_dec=(const float*)d_in[15];
  const float* W_lin_enc=(const float*)d_in[16];
  const float* b_lin_enc=(const float*)d_in[17];
  const float* W_lin_dec=(const float*)d_in[18];
  const float* W_out    =(const float*)d_in[19];
  const float* b_out    =(const float*)d_in[20];
  float* out=(float*)d_out;

  char* wp=(char*)d_ws;
  auto carve=[&](size_t bytes)->char*{ char* p=wp; wp += (bytes+255)&~(size_t)255; return p; };
  u16*   hs_bf  =(u16*)  carve((size_t)B_*T_*D_*2);
  u16*   pe_bf  =(u16*)  carve((size_t)B_*T_*D_*2);
  u16*   WdT    =(u16*)  carve((size_t)512*512*2);
  u16*   Wi0a   =(u16*)  carve((size_t)G_*512*2);
  u16*   Whh0b  =(u16*)  carve((size_t)G_*512*2);
  u16*   Wih1b  =(u16*)  carve((size_t)G_*512*2);
  u16*   Whh1b  =(u16*)  carve((size_t)G_*512*2);
  u16*   WoT    =(u16*)  carve((size_t)512*512*2);
  float* lin_enc=(float*)carve((size_t)B_*T_*512*4);
  float* ey_pre =(float*)carve((size_t)B_*U_*G_*4);
  float* hdec   =(float*)carve((size_t)B_*U_*512*4);
  float* lin_dec=(float*)carve((size_t)B_*U_*512*4);
  float* q_g    =(float*)carve(4096*4);
  float* attc   =(float*)carve(4096*4);
  float* gpart  =(float*)carve((size_t)16384*4);
  float* states =(float*)carve(5*4096*4);
  unsigned* barcnt=(unsigned*)carve(256);
  float* h0g=states;            // 4096
  float* h1g=states+4096;       // 2 x 4096 (ping-pong)
  float* c0g=states+3*4096;
  float* c1g=states+4*4096;

  hipMemsetAsync(states,0,5*4096*4,stream);
  hipMemsetAsync(barcnt,0,256,stream);

  int n1=B_*T_*D_, n2=G_*512;
  k_f2bf    <<<(n1+255)/256,256,0,stream>>>(hs_pad,hs_bf,n1);
  k_trans_bf<<<(512*512+255)/256,256,0,stream>>>(W_att_dec,WdT,512,512);
  k_wi0a    <<<(n2+255)/256,256,0,stream>>>(W_ih0,Wi0a);
  k_f2bf    <<<(n2+255)/256,256,0,stream>>>(W_hh0,Whh0b,n2);
  k_f2bf    <<<(n2+255)/256,256,0,stream>>>(W_ih1,Wih1b,n2);
  k_f2bf    <<<(n2+255)/256,256,0,stream>>>(W_hh1,Whh1b,n2);
  k_woT     <<<(512*512+255)/256,256,0,stream>>>(W_out,WoT);

  // pre GEMMs
  k_gemm<<<dim3(32,8),256,0,stream>>>(hs_pad,nullptr,512, W_att_enc,512,0, b_att_enc,nullptr, 1,1, pe_bf,512, 512);
  k_gemm<<<dim3(32,8),256,0,stream>>>(hs_pad,nullptr,512, W_lin_enc,512,0, b_lin_enc,nullptr, 0,0, lin_enc,512, 512);
  k_gemm<<<dim3(8,32),256,0,stream>>>(emb,ys,512,        W_ih0,1024,1,    b_ih0,b_hh0,      0,0, ey_pre,2048, 512);

  // persistent scan: one launch for all 64 steps
  k_scan<<<NB,256,0,stream>>>(WdT,b_att_dec,pe_bf,hs_bf,hlens,
                              Wi0a,Whh0b,Wih1b,Whh1b,b_ih1,b_hh1,ey_pre,
                              q_g,attc,gpart,h0g,h1g,c0g,c1g,hdec,barcnt);

  // post GEMM + joint
  k_gemm <<<dim3(8,8),256,0,stream>>>(hdec,nullptr,512, W_lin_dec,512,0, nullptr,nullptr, 0,0, lin_dec,512, 512);
  k_joint<<<2048,256,0,stream>>>(lin_enc,lin_dec,WoT,b_out,out);
}

// Round 6
// 5333.989 us; speedup vs baseline: 1.4814x; 1.4814x over previous
//
#include <hip/hip_runtime.h>
#include <cstddef>
#include <cstdint>

typedef unsigned short u16;
typedef __attribute__((ext_vector_type(8))) unsigned short u16x8;
typedef __attribute__((ext_vector_type(8))) short s16x8;
typedef __attribute__((ext_vector_type(4))) float f32x4;

#define B_ 8
#define T_ 256
#define U_ 64
#define D_ 512
#define G_ 2048   // 4*DUNITS
#define OD 500
#define NB 64     // persistent scan blocks (<=256 -> co-residency guaranteed)

__device__ __forceinline__ float bf2f(u16 u){ unsigned v=((unsigned)u)<<16; return __builtin_bit_cast(float,v); }
__device__ __forceinline__ u16 f2bf(float f){ unsigned u=__builtin_bit_cast(unsigned,f); u += 0x7fffu + ((u>>16)&1u); return (u16)(u>>16); }
__device__ __forceinline__ float sigm(float x){ return 1.f/(1.f+expf(-x)); }
__device__ __forceinline__ float wredsum(float v){
  #pragma unroll
  for(int o=32;o;o>>=1) v += __shfl_xor(v,o);
  return v;
}
__device__ __forceinline__ float wredmax(float v){
  #pragma unroll
  for(int o=32;o;o>>=1) v = fmaxf(v,__shfl_xor(v,o));
  return v;
}

// coherent cross-block access: relaxed agent-scope atomics bypass the
// (non-cross-coherent) per-XCD L2 and hit the LLC coherence point directly.
// -> no fences needed anywhere, read-only weights stay L2-hot.
__device__ __forceinline__ float gload(const float* p){
  return __hip_atomic_load(p, __ATOMIC_RELAXED, __HIP_MEMORY_SCOPE_AGENT);
}
__device__ __forceinline__ void gstore(float* p, float v){
  __hip_atomic_store(p, v, __ATOMIC_RELAXED, __HIP_MEMORY_SCOPE_AGENT);
}

// fence-free grid barrier: __syncthreads drains vmcnt(0) per wave (all sc1
// stores at LLC), then one relaxed RMW + relaxed spin. No cache maintenance.
__device__ __forceinline__ void gridbar(unsigned* cnt, unsigned target){
  __syncthreads();
  if(threadIdx.x==0){
    asm volatile("s_waitcnt vmcnt(0)" ::: "memory");
    __hip_atomic_fetch_add(cnt,1u,__ATOMIC_RELAXED,__HIP_MEMORY_SCOPE_AGENT);
    while(__hip_atomic_load(cnt,__ATOMIC_RELAXED,__HIP_MEMORY_SCOPE_AGENT) < target){
      __builtin_amdgcn_s_sleep(1);
    }
  }
  __syncthreads();
}

// ---------------- conversion kernels (one-time per call) ----------------
__global__ void k_f2bf(const float* __restrict__ s, u16* __restrict__ d, int n){
  int i=blockIdx.x*256+threadIdx.x; if(i<n) d[i]=f2bf(s[i]);
}
__global__ void k_trans_bf(const float* __restrict__ s, u16* __restrict__ d, int R, int C){
  int i=blockIdx.x*256+threadIdx.x; if(i>=R*C) return;
  int c=i/R, r=i-c*R; d[i]=f2bf(s[(size_t)r*C+c]);
}
__global__ void k_wi0a(const float* __restrict__ W, u16* __restrict__ d){
  int i=blockIdx.x*256+threadIdx.x; if(i>=G_*D_) return;
  int g=i>>9, e=i&511; d[i]=f2bf(W[(size_t)g*1024 + 512 + e]);
}
__global__ void k_woT(const float* __restrict__ W, u16* __restrict__ d){
  int i=blockIdx.x*256+threadIdx.x; if(i>=512*512) return;
  int o=i>>9, j=i&511; d[i] = (o<OD)? f2bf(W[(size_t)j*OD+o]) : (u16)0;
}

// ---------------- generic bf16-MFMA GEMM ----------------
__global__ __launch_bounds__(256) void k_gemm(
  const float* __restrict__ A, const int* __restrict__ gidx, int lda,
  const float* __restrict__ Bm, int ldb, int bT,
  const float* __restrict__ bias1, const float* __restrict__ bias2,
  int actTanh, int outBf16, void* __restrict__ C, int ldc, int K)
{
  __shared__ __align__(16) u16 As[64][40];
  __shared__ __align__(16) u16 Bs[64][40];
  int tid=threadIdx.x;
  int m0=blockIdx.x*64, n0=blockIdx.y*64;
  int w=tid>>6, l=tid&63;
  f32x4 acc[4];
  #pragma unroll
  for(int nt=0;nt<4;++nt) acc[nt]=(f32x4){0.f,0.f,0.f,0.f};
  int arow=tid>>2, aseg=tid&3;
  int ar = gidx ? gidx[m0+arow] : (m0+arow);
  const float* Ap = A + (size_t)ar*lda + aseg*8;

  for(int kt=0;kt<K/32;++kt){
    const float* ap = Ap + kt*32;
    f32x4 a0=*(const f32x4*)ap, a1=*(const f32x4*)(ap+4);
    #pragma unroll
    for(int i=0;i<4;++i){ As[arow][aseg*8+i]=f2bf(a0[i]); As[arow][aseg*8+4+i]=f2bf(a1[i]); }
    if(bT){
      const float* bp = Bm + (size_t)(n0+arow)*ldb + kt*32 + aseg*8;
      f32x4 b0=*(const f32x4*)bp, b1=*(const f32x4*)(bp+4);
      #pragma unroll
      for(int i=0;i<4;++i){ Bs[arow][aseg*8+i]=f2bf(b0[i]); Bs[arow][aseg*8+4+i]=f2bf(b1[i]); }
    } else {
      int bk=tid>>3, bn=(tid&7)*8;
      const float* bp = Bm + (size_t)(kt*32+bk)*ldb + n0 + bn;
      f32x4 b0=*(const f32x4*)bp, b1=*(const f32x4*)(bp+4);
      #pragma unroll
      for(int i=0;i<4;++i){ Bs[bn+i][bk]=f2bf(b0[i]); Bs[bn+4+i][bk]=f2bf(b1[i]); }
    }
    __syncthreads();
    s16x8 af = *(const s16x8*)&As[w*16 + (l&15)][(l>>4)*8];
    #pragma unroll
    for(int nt=0;nt<4;++nt){
      s16x8 bf = *(const s16x8*)&Bs[nt*16 + (l&15)][(l>>4)*8];
      acc[nt]=__builtin_amdgcn_mfma_f32_16x16x32_bf16(af,bf,acc[nt],0,0,0);
    }
    __syncthreads();
  }
  int mr = w*16 + ((l>>4)<<2), cc = l&15;
  #pragma unroll
  for(int nt=0;nt<4;++nt){
    int gn = n0 + nt*16 + cc;
    float bb = (bias1?bias1[gn]:0.f) + (bias2?bias2[gn]:0.f);
    #pragma unroll
    for(int r=0;r<4;++r){
      int gm = m0 + mr + r;
      float v = acc[nt][r] + bb;
      if(actTanh) v = tanhf(v);
      if(outBf16) ((u16*)C)[(size_t)gm*ldc+gn] = f2bf(v);
      else        ((float*)C)[(size_t)gm*ldc+gn] = v;
    }
  }
}

// ---------------- persistent scan kernel ----------------
// 64 blocks x 256 threads, 3 fence-free grid barriers per step.
// Cross-block state via sc1 (agent-scope relaxed atomics); c0/c1 in registers.
__global__ __launch_bounds__(256) void k_scan(
  const u16* __restrict__ WdT, const float* __restrict__ b_att_dec,
  const u16* __restrict__ pe_bf, const u16* __restrict__ hs_bf, const int* __restrict__ hlens,
  const u16* __restrict__ Wi0a, const u16* __restrict__ Whh0b,
  const u16* __restrict__ Wih1b, const u16* __restrict__ Whh1b,
  const float* __restrict__ b_ih1, const float* __restrict__ b_hh1,
  const float* __restrict__ ey_pre,
  float* __restrict__ q_g, float* __restrict__ attc, float* __restrict__ gpart,
  float* __restrict__ h0g, float* __restrict__ h1g,  // h1g: 2 buffers of 4096
  float* __restrict__ hdec, unsigned* __restrict__ barcnt)
{
  __shared__ float sm[2*8*516 + 512];
  int tid=threadIdx.x, bid=blockIdx.x;
  unsigned baridx=0;
  float* xs=sm; float* hs=sm+8*516; float* gl=sm+2*8*516;
  float c0r=0.f, c1r=0.f;   // cell states for this thread's (b,j) — tid<64 only

  for(int u=0; u<=U_; ++u){
    // ---------- P1: LSTM1(u-1) + q_u ----------
    float* h1prev = h1g + (u&1)*4096;
    float* h1new  = h1g + ((u+1)&1)*4096;
    for(int i=tid;i<4096;i+=256){
      int b=i>>9,k=i&511;
      xs[b*516+k]=gload(h0g+i); hs[b*516+k]=gload(h1prev+i);
    }
    __syncthreads();
    if(u>0){
      int b=tid&7, g=(tid>>3)&3, jj=tid>>5;
      int row=g*512 + bid*8 + jj;
      const u16* w1=Wih1b+(size_t)row*512;
      const u16* w2=Whh1b+(size_t)row*512;
      const float* xr=&xs[b*516]; const float* hr=&hs[b*516];
      float p0=0.f,p1=0.f,p2=0.f,p3=0.f;
      for(int kc=0;kc<64;++kc){
        u16x8 x1=*(const u16x8*)(w1+kc*8);
        u16x8 x2=*(const u16x8*)(w2+kc*8);
        f32x4 xa=*(const f32x4*)(xr+kc*8), xb=*(const f32x4*)(xr+kc*8+4);
        f32x4 ha=*(const f32x4*)(hr+kc*8), hb=*(const f32x4*)(hr+kc*8+4);
        #pragma unroll
        for(int i=0;i<4;++i){
          p0 += bf2f(x1[i])  *xa[i];
          p1 += bf2f(x1[4+i])*xb[i];
          p2 += bf2f(x2[i])  *ha[i];
          p3 += bf2f(x2[4+i])*hb[i];
        }
      }
      gl[jj*32+g*8+b]= b_ih1[row]+b_hh1[row] + (p0+p1)+(p2+p3);
    }
    if(u<U_ && tid<64){
      int idx=bid*64+tid, b=idx>>9, a_=idx&511;
      const u16* wr=WdT+(size_t)a_*512;
      const float* xr=&xs[b*516];
      float p0=0.f,p1=0.f;
      for(int kc=0;kc<64;++kc){
        u16x8 v=*(const u16x8*)(wr+kc*8);
        f32x4 xa=*(const f32x4*)(xr+kc*8), xb=*(const f32x4*)(xr+kc*8+4);
        #pragma unroll
        for(int i=0;i<4;++i){ p0 += bf2f(v[i])*xa[i]; p1 += bf2f(v[4+i])*xb[i]; }
      }
      gstore(q_g+idx, tanhf(p0+p1+b_att_dec[a_]));
    }
    __syncthreads();
    if(u>0 && tid<64){
      int b=tid&7, jj=tid>>3, j=bid*8+jj;
      float i_=sigm(gl[jj*32+0*8+b]), f_=sigm(gl[jj*32+1*8+b]);
      float g_=tanhf(gl[jj*32+2*8+b]), o_=sigm(gl[jj*32+3*8+b]);
      c1r=f_*c1r+i_*g_;
      float h=o_*tanhf(c1r);
      gstore(h1new+b*512+j, h);
      hdec[((size_t)(b*64+(u-1)))*512 + j]=h;
    }
    if(u==U_) break;
    gridbar(barcnt, NB*(++baridx));

    // ---------- P2: attention (blocks 0..7) | gpart = h0@Whh0^T (blocks 8..63) ----------
    if(bid<8){
      int b=bid;
      float* qs=sm; float* ew=sm+512; float* red=sm+512+256; // xs dead for this block
      for(int i=tid;i<512;i+=256) qs[i]=gload(q_g+b*512+i);
      __syncthreads();
      int wv=tid>>6, ln=tid&63, hl=hlens[b];
      for(int t=wv;t<256;t+=4){
        const u16* p = pe_bf + ((size_t)(b*256+t))*512 + ln*8;
        u16x8 v=*(const u16x8*)p;
        float a=0.f;
        #pragma unroll
        for(int i=0;i<8;++i) a += bf2f(v[i])*qs[ln*8+i];
        a=wredsum(a);
        if(ln==0) ew[t]=(t<hl)? a : -1e30f;
      }
      __syncthreads();
      float val=ew[tid];
      float m=wredmax(val);
      if(ln==0) red[wv]=m;
      __syncthreads();
      float M=fmaxf(fmaxf(red[0],red[1]),fmaxf(red[2],red[3]));
      float p=expf(val-M);
      float s=wredsum(p);
      if(ln==0) red[4+wv]=s;
      __syncthreads();
      float S=red[4]+red[5]+red[6]+red[7];
      ew[tid]=p/S;
      __syncthreads();
      for(int d=tid;d<512;d+=256){
        const u16* hp=hs_bf+(size_t)b*256*512+d;
        float a0=0.f,a1=0.f,a2=0.f,a3=0.f;
        for(int t=0;t<256;t+=4){
          a0+=ew[t  ]*bf2f(hp[(size_t)(t  )*512]);
          a1+=ew[t+1]*bf2f(hp[(size_t)(t+1)*512]);
          a2+=ew[t+2]*bf2f(hp[(size_t)(t+2)*512]);
          a3+=ew[t+3]*bf2f(hp[(size_t)(t+3)*512]);
        }
        gstore(attc+b*512+d,(a0+a1)+(a2+a3));
      }
    } else {
      for(int idx=(bid-8)*256+tid; idx<16384; idx+=56*256){
        int b=idx&7, row=idx>>3;
        const u16* w=Whh0b+(size_t)row*512;
        const float* xr=&xs[b*516];
        float p0=0.f,p1=0.f,p2=0.f,p3=0.f;
        for(int kc=0;kc<64;++kc){
          u16x8 x=*(const u16x8*)(w+kc*8);
          f32x4 xa=*(const f32x4*)(xr+kc*8), xb=*(const f32x4*)(xr+kc*8+4);
          p0+=bf2f(x[0])*xa[0]+bf2f(x[2])*xa[2];
          p1+=bf2f(x[1])*xa[1]+bf2f(x[3])*xa[3];
          p2+=bf2f(x[4])*xb[0]+bf2f(x[6])*xb[2];
          p3+=bf2f(x[5])*xb[1]+bf2f(x[7])*xb[3];
        }
        gstore(gpart+(size_t)row*8+b,(p0+p1)+(p2+p3));
      }
    }
    gridbar(barcnt, NB*(++baridx));

    // ---------- P3: gates0 = ey + gpart + attc@Wi0a^T ----------
    for(int i=tid;i<4096;i+=256){ int b=i>>9,k=i&511; xs[b*516+k]=gload(attc+i); }
    __syncthreads();
    {
      int b=tid&7, g=(tid>>3)&3, jj=tid>>5;
      int row=g*512 + bid*8 + jj;
      const u16* w=Wi0a+(size_t)row*512;
      const float* xr=&xs[b*516];
      float p0=0.f,p1=0.f,p2=0.f,p3=0.f;
      for(int kc=0;kc<64;++kc){
        u16x8 x=*(const u16x8*)(w+kc*8);
        f32x4 xa=*(const f32x4*)(xr+kc*8), xb=*(const f32x4*)(xr+kc*8+4);
        p0+=bf2f(x[0])*xa[0]+bf2f(x[2])*xa[2];
        p1+=bf2f(x[1])*xa[1]+bf2f(x[3])*xa[3];
        p2+=bf2f(x[4])*xb[0]+bf2f(x[6])*xb[2];
        p3+=bf2f(x[5])*xb[1]+bf2f(x[7])*xb[3];
      }
      gl[jj*32+g*8+b]= ey_pre[((size_t)((b<<6)|u))*2048 + row]
                      + gload(gpart+(size_t)row*8+b) + (p0+p1)+(p2+p3);
    }
    __syncthreads();
    if(tid<64){
      int b=tid&7, jj=tid>>3, j=bid*8+jj;
      float i_=sigm(gl[jj*32+0*8+b]), f_=sigm(gl[jj*32+1*8+b]);
      float g_=tanhf(gl[jj*32+2*8+b]), o_=sigm(gl[jj*32+3*8+b]);
      c0r=f_*c0r+i_*g_;
      gstore(h0g+b*512+j, o_*tanhf(c0r));
    }
    gridbar(barcnt, NB*(++baridx));
  }
}

// ---------------- joint network ----------------
__global__ __launch_bounds__(256) void k_joint(
  const float* __restrict__ lin_enc, const float* __restrict__ lin_dec,
  const u16* __restrict__ WoT, const float* __restrict__ b_out,
  float* __restrict__ out)
{
  __shared__ __align__(16) u16 As[64*512];
  __shared__ float ld_s[512];
  int tid=threadIdx.x, bid=blockIdx.x;
  int b=bid>>8, u=(bid>>2)&63, t0=(bid&3)*64;
  for(int i=tid;i<512;i+=256) ld_s[i]=lin_dec[((size_t)((b<<6)|u))*512 + i];
  __syncthreads();
  const float* le = lin_enc + ((size_t)(b*256 + t0))*512;
  for(int it=0;it<16;++it){
    int idx=it*256+tid;
    int row=idx>>6, c0=(idx&63)*8;
    f32x4 x0=*(const f32x4*)(le + (size_t)row*512 + c0);
    f32x4 x1=*(const f32x4*)(le + (size_t)row*512 + c0 + 4);
    u16x8 pk;
    #pragma unroll
    for(int i=0;i<4;++i){
      pk[i]  =f2bf(tanhf(x0[i]+ld_s[c0+i]));
      pk[4+i]=f2bf(tanhf(x1[i]+ld_s[c0+4+i]));
    }
    int sc = c0 ^ ((row&7)<<3);
    *(u16x8*)&As[row*512+sc]=pk;
  }
  __syncthreads();
  int w=tid>>6, l=tid&63;
  for(int ch=0;ch<8;++ch){
    int n0=ch*64 + w*16;
    int o = n0 + (l&15);
    s16x8 bfr[16];
    const u16* wp = WoT + (size_t)o*512 + ((l>>4)*8);
    #pragma unroll
    for(int ks=0;ks<16;++ks) bfr[ks]=*(const s16x8*)(wp + ks*32);
    float bo = (o<OD)? b_out[o] : 0.f;
    for(int mt=0;mt<4;++mt){
      f32x4 acc=(f32x4){0.f,0.f,0.f,0.f};
      int row = mt*16 + (l&15);
      int sw  = (row&7)<<3;
      #pragma unroll
      for(int ks=0;ks<16;++ks){
        int cidx=(ks*32 + (l>>4)*8) ^ sw;
        s16x8 af=*(const s16x8*)&As[row*512+cidx];
        acc=__builtin_amdgcn_mfma_f32_16x16x32_bf16(af,bfr[ks],acc,0,0,0);
      }
      if(o<OD){
        #pragma unroll
        for(int r=0;r<4;++r){
          int t = t0 + mt*16 + ((l>>4)<<2) + r;
          out[(((size_t)(b*256+t))*64 + u)*500 + o] = acc[r] + bo;
        }
      }
    }
  }
}

// ---------------- host launcher ----------------
extern "C" void kernel_launch(void* const* d_in, const int* in_sizes, int n_in,
                              void* d_out, int out_size, void* d_ws, size_t ws_size,
                              hipStream_t stream)
{
  (void)in_sizes; (void)n_in; (void)out_size; (void)ws_size;
  const float* hs_pad   =(const float*)d_in[0];
  const int*   ys       =(const int*)  d_in[1];
  const int*   hlens    =(const int*)  d_in[2];
  const float* emb      =(const float*)d_in[3];
  const float* W_ih0    =(const float*)d_in[4];
  const float* W_hh0    =(const float*)d_in[5];
  const float* b_ih0    =(const float*)d_in[6];
  const float* b_hh0    =(const float*)d_in[7];
  const float* W_ih1    =(const float*)d_in[8];
  const float* W_hh1    =(const float*)d_in[9];
  const float* b_ih1    =(const float*)d_in[10];
  const float* b_hh1    =(const float*)d_in[11];
  const float* W_att_enc=(const float*)d_in[12];
  const float* b_att_enc=(const float*)d_in[13];
  const float* W_att_dec=(const float*)d_in[14];
  const float* b_att_dec=(const float*)d_in[15];
  const float* W_lin_enc=(const float*)d_in[16];
  const float* b_lin_enc=(const float*)d_in[17];
  const float* W_lin_dec=(const float*)d_in[18];
  const float* W_out    =(const float*)d_in[19];
  const float* b_out    =(const float*)d_in[20];
  float* out=(float*)d_out;

  char* wp=(char*)d_ws;
  auto carve=[&](size_t bytes)->char*{ char* p=wp; wp += (bytes+255)&~(size_t)255; return p; };
  u16*   hs_bf  =(u16*)  carve((size_t)B_*T_*D_*2);
  u16*   pe_bf  =(u16*)  carve((size_t)B_*T_*D_*2);
  u16*   WdT    =(u16*)  carve((size_t)512*512*2);
  u16*   Wi0a   =(u16*)  carve((size_t)G_*512*2);
  u16*   Whh0b  =(u16*)  carve((size_t)G_*512*2);
  u16*   Wih1b  =(u16*)  carve((size_t)G_*512*2);
  u16*   Whh1b  =(u16*)  carve((size_t)G_*512*2);
  u16*   WoT    =(u16*)  carve((size_t)512*512*2);
  float* lin_enc=(float*)carve((size_t)B_*T_*512*4);
  float* ey_pre =(float*)carve((size_t)B_*U_*G_*4);
  float* hdec   =(float*)carve((size_t)B_*U_*512*4);
  float* lin_dec=(float*)carve((size_t)B_*U_*512*4);
  float* q_g    =(float*)carve(4096*4);
  float* attc   =(float*)carve(4096*4);
  float* gpart  =(float*)carve((size_t)16384*4);
  float* states =(float*)carve(3*4096*4);
  unsigned* barcnt=(unsigned*)carve(256);
  float* h0g=states;            // 4096
  float* h1g=states+4096;       // 2 x 4096 (ping-pong)

  hipMemsetAsync(states,0,3*4096*4,stream);
  hipMemsetAsync(barcnt,0,256,stream);

  int n1=B_*T_*D_, n2=G_*512;
  k_f2bf    <<<(n1+255)/256,256,0,stream>>>(hs_pad,hs_bf,n1);
  k_trans_bf<<<(512*512+255)/256,256,0,stream>>>(W_att_dec,WdT,512,512);
  k_wi0a    <<<(n2+255)/256,256,0,stream>>>(W_ih0,Wi0a);
  k_f2bf    <<<(n2+255)/256,256,0,stream>>>(W_hh0,Whh0b,n2);
  k_f2bf    <<<(n2+255)/256,256,0,stream>>>(W_ih1,Wih1b,n2);
  k_f2bf    <<<(n2+255)/256,256,0,stream>>>(W_hh1,Whh1b,n2);
  k_woT     <<<(512*512+255)/256,256,0,stream>>>(W_out,WoT);

  // pre GEMMs
  k_gemm<<<dim3(32,8),256,0,stream>>>(hs_pad,nullptr,512, W_att_enc,512,0, b_att_enc,nullptr, 1,1, pe_bf,512, 512);
  k_gemm<<<dim3(32,8),256,0,stream>>>(hs_pad,nullptr,512, W_lin_enc,512,0, b_lin_enc,nullptr, 0,0, lin_enc,512, 512);
  k_gemm<<<dim3(8,32),256,0,stream>>>(emb,ys,512,        W_ih0,1024,1,    b_ih0,b_hh0,      0,0, ey_pre,2048, 512);

  // persistent scan: one launch for all 64 steps
  k_scan<<<NB,256,0,stream>>>(WdT,b_att_dec,pe_bf,hs_bf,hlens,
                              Wi0a,Whh0b,Wih1b,Whh1b,b_ih1,b_hh1,ey_pre,
                              q_g,attc,gpart,h0g,h1g,hdec,barcnt);

  // post GEMM + joint
  k_gemm <<<dim3(8,8),256,0,stream>>>(hdec,nullptr,512, W_lin_dec,512,0, nullptr,nullptr, 0,0, lin_dec,512, 512);
  k_joint<<<2048,256,0,stream>>>(lin_enc,lin_dec,WoT,b_out,out);
}

// Round 7
// 4069.940 us; speedup vs baseline: 1.9415x; 1.3106x over previous
//
#include <hip/hip_runtime.h>
#include <cstddef>
#include <cstdint>

typedef unsigned short u16;
typedef __attribute__((ext_vector_type(8))) unsigned short u16x8;
typedef __attribute__((ext_vector_type(8))) short s16x8;
typedef __attribute__((ext_vector_type(4))) float f32x4;

#define B_ 8
#define T_ 256
#define U_ 64
#define D_ 512
#define G_ 2048   // 4*DUNITS
#define OD 500
#define NBLK 136  // 8 attention + 128 LSTM blocks (<=256 -> co-resident)

__device__ __forceinline__ float bf2f(u16 u){ unsigned v=((unsigned)u)<<16; return __builtin_bit_cast(float,v); }
__device__ __forceinline__ u16 f2bf(float f){ unsigned u=__builtin_bit_cast(unsigned,f); u += 0x7fffu + ((u>>16)&1u); return (u16)(u>>16); }
__device__ __forceinline__ float sigm(float x){ return 1.f/(1.f+expf(-x)); }
__device__ __forceinline__ float wredsum(float v){
  #pragma unroll
  for(int o=32;o;o>>=1) v += __shfl_xor(v,o);
  return v;
}
__device__ __forceinline__ float wredmax(float v){
  #pragma unroll
  for(int o=32;o;o>>=1) v = fmaxf(v,__shfl_xor(v,o));
  return v;
}

// coherent cross-block access: relaxed agent-scope atomics execute at the LLC
// coherence point (proven correct in r5/r6). No fences -> weights stay L2-hot.
__device__ __forceinline__ float gload(const float* p){
  return __hip_atomic_load(p, __ATOMIC_RELAXED, __HIP_MEMORY_SCOPE_AGENT);
}
__device__ __forceinline__ void gstore(float* p, float v){
  __hip_atomic_store(p, v, __ATOMIC_RELAXED, __HIP_MEMORY_SCOPE_AGENT);
}

// fence-free monotonic grid barrier
__device__ __forceinline__ void gridbar(unsigned* cnt, unsigned target){
  __syncthreads();
  if(threadIdx.x==0){
    asm volatile("s_waitcnt vmcnt(0)" ::: "memory");
    __hip_atomic_fetch_add(cnt,1u,__ATOMIC_RELAXED,__HIP_MEMORY_SCOPE_AGENT);
    while(__hip_atomic_load(cnt,__ATOMIC_RELAXED,__HIP_MEMORY_SCOPE_AGENT) < target){
      __builtin_amdgcn_s_sleep(2);
    }
  }
  __syncthreads();
}

// ---------------- conversion kernels (one-time per call) ----------------
__global__ void k_f2bf(const float* __restrict__ s, u16* __restrict__ d, int n){
  int i=blockIdx.x*256+threadIdx.x; if(i<n) d[i]=f2bf(s[i]);
}
__global__ void k_trans_bf(const float* __restrict__ s, u16* __restrict__ d, int R, int C){
  int i=blockIdx.x*256+threadIdx.x; if(i>=R*C) return;
  int c=i/R, r=i-c*R; d[i]=f2bf(s[(size_t)r*C+c]);
}
__global__ void k_wi0a(const float* __restrict__ W, u16* __restrict__ d){
  int i=blockIdx.x*256+threadIdx.x; if(i>=G_*D_) return;
  int g=i>>9, e=i&511; d[i]=f2bf(W[(size_t)g*1024 + 512 + e]);
}
__global__ void k_woT(const float* __restrict__ W, u16* __restrict__ d){
  int i=blockIdx.x*256+threadIdx.x; if(i>=512*512) return;
  int o=i>>9, j=i&511; d[i] = (o<OD)? f2bf(W[(size_t)j*OD+o]) : (u16)0;
}
// hs_bfT[b][d][t] = bf16(hs_pad[b][t][d])  -- contiguous-in-t for attc
__global__ void k_transT(const float* __restrict__ hs, u16* __restrict__ d){
  int i=blockIdx.x*256+threadIdx.x; if(i>=B_*D_*T_) return;
  int t=i&255, dd=(i>>8)&511, b=i>>17;
  d[i]=f2bf(hs[((size_t)(b*256+t))*512 + dd]);
}

// ---------------- generic bf16-MFMA GEMM (pre/post passes) ----------------
__global__ __launch_bounds__(256) void k_gemm(
  const float* __restrict__ A, const int* __restrict__ gidx, int lda,
  const float* __restrict__ Bm, int ldb, int bT,
  const float* __restrict__ bias1, const float* __restrict__ bias2,
  int actTanh, int outBf16, void* __restrict__ C, int ldc, int K)
{
  __shared__ __align__(16) u16 As[64][40];
  __shared__ __align__(16) u16 Bs[64][40];
  int tid=threadIdx.x;
  int m0=blockIdx.x*64, n0=blockIdx.y*64;
  int w=tid>>6, l=tid&63;
  f32x4 acc[4];
  #pragma unroll
  for(int nt=0;nt<4;++nt) acc[nt]=(f32x4){0.f,0.f,0.f,0.f};
  int arow=tid>>2, aseg=tid&3;
  int ar = gidx ? gidx[m0+arow] : (m0+arow);
  const float* Ap = A + (size_t)ar*lda + aseg*8;

  for(int kt=0;kt<K/32;++kt){
    const float* ap = Ap + kt*32;
    f32x4 a0=*(const f32x4*)ap, a1=*(const f32x4*)(ap+4);
    #pragma unroll
    for(int i=0;i<4;++i){ As[arow][aseg*8+i]=f2bf(a0[i]); As[arow][aseg*8+4+i]=f2bf(a1[i]); }
    if(bT){
      const float* bp = Bm + (size_t)(n0+arow)*ldb + kt*32 + aseg*8;
      f32x4 b0=*(const f32x4*)bp, b1=*(const f32x4*)(bp+4);
      #pragma unroll
      for(int i=0;i<4;++i){ Bs[arow][aseg*8+i]=f2bf(b0[i]); Bs[arow][aseg*8+4+i]=f2bf(b1[i]); }
    } else {
      int bk=tid>>3, bn=(tid&7)*8;
      const float* bp = Bm + (size_t)(kt*32+bk)*ldb + n0 + bn;
      f32x4 b0=*(const f32x4*)bp, b1=*(const f32x4*)(bp+4);
      #pragma unroll
      for(int i=0;i<4;++i){ Bs[bn+i][bk]=f2bf(b0[i]); Bs[bn+4+i][bk]=f2bf(b1[i]); }
    }
    __syncthreads();
    s16x8 af = *(const s16x8*)&As[w*16 + (l&15)][(l>>4)*8];
    #pragma unroll
    for(int nt=0;nt<4;++nt){
      s16x8 bf = *(const s16x8*)&Bs[nt*16 + (l&15)][(l>>4)*8];
      acc[nt]=__builtin_amdgcn_mfma_f32_16x16x32_bf16(af,bf,acc[nt],0,0,0);
    }
    __syncthreads();
  }
  int mr = w*16 + ((l>>4)<<2), cc = l&15;
  #pragma unroll
  for(int nt=0;nt<4;++nt){
    int gn = n0 + nt*16 + cc;
    float bb = (bias1?bias1[gn]:0.f) + (bias2?bias2[gn]:0.f);
    #pragma unroll
    for(int r=0;r<4;++r){
      int gm = m0 + mr + r;
      float v = acc[nt][r] + bb;
      if(actTanh) v = tanhf(v);
      if(outBf16) ((u16*)C)[(size_t)gm*ldc+gn] = f2bf(v);
      else        ((float*)C)[(size_t)gm*ldc+gn] = v;
    }
  }
}

// one 16(rows)x16(batch)xK matvec unit on MFMA.
// A: lane l&15 -> weight row R(l&15) (interleaved: g=rl>>2, jj=rl&3);
// B: lane l&15 -> batch col, 8 bf16 k's per lane from the LDS x-panel.
__device__ __forceinline__ f32x4 mfma_unit(const u16* __restrict__ Wb, const u16* xb,
                                           int lb, int l, int k0, int nks){
  int rl=l&15;
  int row = ((rl>>2)<<9) + (lb<<2) + (rl&3);
  const u16* wp = Wb + (size_t)row*512 + k0 + ((l>>4)*8);
  const u16* xp = xb + (size_t)rl*520 + k0 + ((l>>4)*8);
  f32x4 acc=(f32x4){0.f,0.f,0.f,0.f};
  for(int ks=0;ks<nks;++ks){
    s16x8 af=*(const s16x8*)(wp + ks*32);
    s16x8 bf=*(const s16x8*)(xp + ks*32);
    acc=__builtin_amdgcn_mfma_f32_16x16x32_bf16(af,bf,acc,0,0,0);
  }
  return acc;
}

// ---------------- persistent scan kernel ----------------
// 136 blocks x 256 thr, 2 grid barriers/step.
// blocks 0..7   : batch-local q -> e -> softmax -> attc          (phase A)
// blocks 8..135 : LSTM1(u-1) + gpart=Whh0*h0 on MFMA (A); LSTM0 on MFMA (B)
// LSTM block lb owns j in [lb*4,lb*4+4) x 4 gates -> epilogue + c-state local.
__global__ __launch_bounds__(256) void k_scan(
  const u16* __restrict__ WdT, const float* __restrict__ b_att_dec,
  const u16* __restrict__ pe_bf, const u16* __restrict__ hs_bfT, const int* __restrict__ hlens,
  const u16* __restrict__ Wi0a, const u16* __restrict__ Whh0b,
  const u16* __restrict__ Wih1b, const u16* __restrict__ Whh1b,
  const float* __restrict__ b_ih1, const float* __restrict__ b_hh1,
  const float* __restrict__ ey_pre,
  float* __restrict__ attc, float* __restrict__ h0g, float* __restrict__ h1g,
  float* __restrict__ hdec, unsigned* __restrict__ barcnt)
{
  __shared__ __align__(16) char smraw[38400];
  int tid=threadIdx.x, bid=blockIdx.x;
  unsigned baridx=0;

  if(bid>=8){
    int lb=bid-8, w=tid>>6, l=tid&63;
    u16*  xbf=(u16*)smraw;              // 16x520 bf16 x-panel (h0 / attc)
    u16*  hbf=(u16*)(smraw+16640);      // 16x520 bf16 h1prev
    float* gl=(float*)(smraw+33280);    // [4][16][16] C-frag dump
    float* gp=(float*)(smraw+37376);    // [16][16] Whh0 partial, survives barrier
    for(int i=tid;i<16*520;i+=256){ xbf[i]=0; hbf[i]=0; }  // cols 8..15 stay 0
    float c0r=0.f, c1r=0.f;
    int jj=(tid>>3)&3, b=tid&7;         // epilogue cell for tid<32

    for(int u=0;u<=U_;++u){
      float* h1prev=h1g+(u&1)*4096;
      float* h1new =h1g+((u+1)&1)*4096;
      // ---- phase A: stage h0,h1prev; MFMA Wih1/Whh1/Whh0; h1 epilogue ----
      for(int i=tid;i<4096;i+=256){
        int bb=i>>9,k=i&511;
        xbf[bb*520+k]=f2bf(gload(h0g+i));
        hbf[bb*520+k]=f2bf(gload(h1prev+i));
      }
      __syncthreads();
      f32x4 acc;
      if(w==0)      acc=mfma_unit(Wih1b,xbf,lb,l,0,16);
      else if(w==1) acc=mfma_unit(Whh1b,hbf,lb,l,0,16);
      else if(w==2) acc=mfma_unit(Whh0b,xbf,lb,l,0,8);
      else          acc=mfma_unit(Whh0b,xbf,lb,l,256,8);
      {
        float* gld=gl+w*256;
        #pragma unroll
        for(int r=0;r<4;++r) gld[((l>>4)*4+r)*16+(l&15)]=acc[r];
      }
      __syncthreads();
      gp[tid]=gl[512+tid]+gl[768+tid];      // Whh0 k-halves combined
      if(u>0 && tid<32){
        int j=lb*4+jj;
        float gv[4];
        #pragma unroll
        for(int g=0;g<4;++g){
          int ridx=g*4+jj, row=g*512+j;
          gv[g]=gl[ridx*16+b]+gl[256+ridx*16+b]+b_ih1[row]+b_hh1[row];
        }
        float i_=sigm(gv[0]), f_=sigm(gv[1]), g_=tanhf(gv[2]), o_=sigm(gv[3]);
        c1r=f_*c1r+i_*g_;
        float h=o_*tanhf(c1r);
        gstore(h1new+b*512+j,h);
        hdec[((size_t)(b*64+(u-1)))*512+j]=h;
      }
      if(u==U_) break;
      gridbar(barcnt,NBLK*(++baridx));

      // ---- phase B: LSTM0 = ey + gpart + Wi0a*attc ----
      for(int i=tid;i<4096;i+=256){ int bb=i>>9,k=i&511; xbf[bb*520+k]=f2bf(gload(attc+i)); }
      __syncthreads();
      acc=mfma_unit(Wi0a,xbf,lb,l,w*128,4);
      {
        float* gld=gl+w*256;
        #pragma unroll
        for(int r=0;r<4;++r) gld[((l>>4)*4+r)*16+(l&15)]=acc[r];
      }
      __syncthreads();
      if(tid<32){
        int j=lb*4+jj;
        float gv[4];
        #pragma unroll
        for(int g=0;g<4;++g){
          int ridx=g*4+jj, row=g*512+j;
          gv[g]=gl[ridx*16+b]+gl[256+ridx*16+b]+gl[512+ridx*16+b]+gl[768+ridx*16+b]
               +gp[ridx*16+b]+ey_pre[((size_t)((b<<6)|u))*2048+row];
        }
        float i_=sigm(gv[0]), f_=sigm(gv[1]), g_=tanhf(gv[2]), o_=sigm(gv[3]);
        c0r=f_*c0r+i_*g_;
        gstore(h0g+b*512+j,o_*tanhf(c0r));
      }
      gridbar(barcnt,NBLK*(++baridx));
    }
  } else {
    // ---- attention block, batch b ----
    int b=bid;
    float* h0s=(float*)smraw;
    float* qs =(float*)(smraw+2048);
    float* ew =(float*)(smraw+4096);
    float* red=(float*)(smraw+5120);
    int wv=tid>>6, ln=tid&63;
    for(int u=0;u<=U_;++u){
      if(u<U_){
        for(int i=tid;i<512;i+=256) h0s[i]=gload(h0g+b*512+i);
        __syncthreads();
        #pragma unroll
        for(int rep=0;rep<2;++rep){
          int a_=tid+rep*256;
          const u16* wr=WdT+(size_t)a_*512;
          float p0=0.f,p1=0.f,p2=0.f,p3=0.f;
          for(int kc=0;kc<64;++kc){
            u16x8 v=*(const u16x8*)(wr+kc*8);
            f32x4 xa=*(const f32x4*)(h0s+kc*8), xb2=*(const f32x4*)(h0s+kc*8+4);
            p0+=bf2f(v[0])*xa[0]+bf2f(v[2])*xa[2];
            p1+=bf2f(v[1])*xa[1]+bf2f(v[3])*xa[3];
            p2+=bf2f(v[4])*xb2[0]+bf2f(v[6])*xb2[2];
            p3+=bf2f(v[5])*xb2[1]+bf2f(v[7])*xb2[3];
          }
          qs[a_]=tanhf((p0+p1)+(p2+p3)+b_att_dec[a_]);
        }
        __syncthreads();
        int hl=hlens[b];
        for(int t=wv;t<256;t+=4){
          const u16* p=pe_bf+((size_t)(b*256+t))*512+ln*8;
          u16x8 v=*(const u16x8*)p;
          float a=0.f;
          #pragma unroll
          for(int i=0;i<8;++i) a+=bf2f(v[i])*qs[ln*8+i];
          a=wredsum(a);
          if(ln==0) ew[t]=(t<hl)?a:-1e30f;
        }
        __syncthreads();
        float val=ew[tid];
        float m=wredmax(val);
        if(ln==0) red[wv]=m;
        __syncthreads();
        float M=fmaxf(fmaxf(red[0],red[1]),fmaxf(red[2],red[3]));
        float p=expf(val-M);
        float s=wredsum(p);
        if(ln==0) red[4+wv]=s;
        __syncthreads();
        float S=red[4]+red[5]+red[6]+red[7];
        ew[tid]=p/S;
        __syncthreads();
        for(int d=tid;d<512;d+=256){
          const u16* hp=hs_bfT+((size_t)(b*512+d))*256;
          float p0=0.f,p1=0.f,p2=0.f,p3=0.f;
          for(int tc=0;tc<32;++tc){
            u16x8 v=*(const u16x8*)(hp+tc*8);
            f32x4 e0=*(const f32x4*)(ew+tc*8), e1=*(const f32x4*)(ew+tc*8+4);
            p0+=e0[0]*bf2f(v[0])+e0[2]*bf2f(v[2]);
            p1+=e0[1]*bf2f(v[1])+e0[3]*bf2f(v[3]);
            p2+=e1[0]*bf2f(v[4])+e1[2]*bf2f(v[6]);
            p3+=e1[1]*bf2f(v[5])+e1[3]*bf2f(v[7]);
          }
          gstore(attc+b*512+d,(p0+p1)+(p2+p3));
        }
      }
      if(u==U_) break;
      gridbar(barcnt,NBLK*(++baridx));
      gridbar(barcnt,NBLK*(++baridx));
    }
  }
}

// ---------------- joint network ----------------
__global__ __launch_bounds__(256) void k_joint(
  const float* __restrict__ lin_enc, const float* __restrict__ lin_dec,
  const u16* __restrict__ WoT, const float* __restrict__ b_out,
  float* __restrict__ out)
{
  __shared__ __align__(16) u16 As[64*512];
  __shared__ float ld_s[512];
  int tid=threadIdx.x, bid=blockIdx.x;
  int b=bid>>8, u=(bid>>2)&63, t0=(bid&3)*64;
  for(int i=tid;i<512;i+=256) ld_s[i]=lin_dec[((size_t)((b<<6)|u))*512 + i];
  __syncthreads();
  const float* le = lin_enc + ((size_t)(b*256 + t0))*512;
  for(int it=0;it<16;++it){
    int idx=it*256+tid;
    int row=idx>>6, c0=(idx&63)*8;
    f32x4 x0=*(const f32x4*)(le + (size_t)row*512 + c0);
    f32x4 x1=*(const f32x4*)(le + (size_t)row*512 + c0 + 4);
    u16x8 pk;
    #pragma unroll
    for(int i=0;i<4;++i){
      pk[i]  =f2bf(tanhf(x0[i]+ld_s[c0+i]));
      pk[4+i]=f2bf(tanhf(x1[i]+ld_s[c0+4+i]));
    }
    int sc = c0 ^ ((row&7)<<3);
    *(u16x8*)&As[row*512+sc]=pk;
  }
  __syncthreads();
  int w=tid>>6, l=tid&63;
  for(int ch=0;ch<8;++ch){
    int n0=ch*64 + w*16;
    int o = n0 + (l&15);
    s16x8 bfr[16];
    const u16* wp = WoT + (size_t)o*512 + ((l>>4)*8);
    #pragma unroll
    for(int ks=0;ks<16;++ks) bfr[ks]=*(const s16x8*)(wp + ks*32);
    float bo = (o<OD)? b_out[o] : 0.f;
    for(int mt=0;mt<4;++mt){
      f32x4 acc=(f32x4){0.f,0.f,0.f,0.f};
      int row = mt*16 + (l&15);
      int sw  = (row&7)<<3;
      #pragma unroll
      for(int ks=0;ks<16;++ks){
        int cidx=(ks*32 + (l>>4)*8) ^ sw;
        s16x8 af=*(const s16x8*)&As[row*512+cidx];
        acc=__builtin_amdgcn_mfma_f32_16x16x32_bf16(af,bfr[ks],acc,0,0,0);
      }
      if(o<OD){
        #pragma unroll
        for(int r=0;r<4;++r){
          int t = t0 + mt*16 + ((l>>4)<<2) + r;
          out[(((size_t)(b*256+t))*64 + u)*500 + o] = acc[r] + bo;
        }
      }
    }
  }
}

// ---------------- host launcher ----------------
extern "C" void kernel_launch(void* const* d_in, const int* in_sizes, int n_in,
                              void* d_out, int out_size, void* d_ws, size_t ws_size,
                              hipStream_t stream)
{
  (void)in_sizes; (void)n_in; (void)out_size; (void)ws_size;
  const float* hs_pad   =(const float*)d_in[0];
  const int*   ys       =(const int*)  d_in[1];
  const int*   hlens    =(const int*)  d_in[2];
  const float* emb      =(const float*)d_in[3];
  const float* W_ih0    =(const float*)d_in[4];
  const float* W_hh0    =(const float*)d_in[5];
  const float* b_ih0    =(const float*)d_in[6];
  const float* b_hh0    =(const float*)d_in[7];
  const float* W_ih1    =(const float*)d_in[8];
  const float* W_hh1    =(const float*)d_in[9];
  const float* b_ih1    =(const float*)d_in[10];
  const float* b_hh1    =(const float*)d_in[11];
  const float* W_att_enc=(const float*)d_in[12];
  const float* b_att_enc=(const float*)d_in[13];
  const float* W_att_dec=(const float*)d_in[14];
  const float* b_att_dec=(const float*)d_in[15];
  const float* W_lin_enc=(const float*)d_in[16];
  const float* b_lin_enc=(const float*)d_in[17];
  const float* W_lin_dec=(const float*)d_in[18];
  const float* W_out    =(const float*)d_in[19];
  const float* b_out    =(const float*)d_in[20];
  float* out=(float*)d_out;

  char* wp=(char*)d_ws;
  auto carve=[&](size_t bytes)->char*{ char* p=wp; wp += (bytes+255)&~(size_t)255; return p; };
  u16*   hs_bfT =(u16*)  carve((size_t)B_*D_*T_*2);
  u16*   pe_bf  =(u16*)  carve((size_t)B_*T_*D_*2);
  u16*   WdT    =(u16*)  carve((size_t)512*512*2);
  u16*   Wi0a   =(u16*)  carve((size_t)G_*512*2);
  u16*   Whh0b  =(u16*)  carve((size_t)G_*512*2);
  u16*   Wih1b  =(u16*)  carve((size_t)G_*512*2);
  u16*   Whh1b  =(u16*)  carve((size_t)G_*512*2);
  u16*   WoT    =(u16*)  carve((size_t)512*512*2);
  float* lin_enc=(float*)carve((size_t)B_*T_*512*4);
  float* ey_pre =(float*)carve((size_t)B_*U_*G_*4);
  float* hdec   =(float*)carve((size_t)B_*U_*512*4);
  float* lin_dec=(float*)carve((size_t)B_*U_*512*4);
  float* attc   =(float*)carve(4096*4);
  float* states =(float*)carve(3*4096*4);
  unsigned* barcnt=(unsigned*)carve(256);
  float* h0g=states;            // 4096
  float* h1g=states+4096;       // 2 x 4096 (ping-pong)

  hipMemsetAsync(states,0,3*4096*4,stream);
  hipMemsetAsync(barcnt,0,256,stream);

  int nT=B_*D_*T_, n2=G_*512;
  k_transT  <<<(nT+255)/256,256,0,stream>>>(hs_pad,hs_bfT);
  k_trans_bf<<<(512*512+255)/256,256,0,stream>>>(W_att_dec,WdT,512,512);
  k_wi0a    <<<(n2+255)/256,256,0,stream>>>(W_ih0,Wi0a);
  k_f2bf    <<<(n2+255)/256,256,0,stream>>>(W_hh0,Whh0b,n2);
  k_f2bf    <<<(n2+255)/256,256,0,stream>>>(W_ih1,Wih1b,n2);
  k_f2bf    <<<(n2+255)/256,256,0,stream>>>(W_hh1,Whh1b,n2);
  k_woT     <<<(512*512+255)/256,256,0,stream>>>(W_out,WoT);

  // pre GEMMs
  k_gemm<<<dim3(32,8),256,0,stream>>>(hs_pad,nullptr,512, W_att_enc,512,0, b_att_enc,nullptr, 1,1, pe_bf,512, 512);
  k_gemm<<<dim3(32,8),256,0,stream>>>(hs_pad,nullptr,512, W_lin_enc,512,0, b_lin_enc,nullptr, 0,0, lin_enc,512, 512);
  k_gemm<<<dim3(8,32),256,0,stream>>>(emb,ys,512,        W_ih0,1024,1,    b_ih0,b_hh0,      0,0, ey_pre,2048, 512);

  // persistent scan: one launch for all 64 steps
  k_scan<<<NBLK,256,0,stream>>>(WdT,b_att_dec,pe_bf,hs_bfT,hlens,
                                Wi0a,Whh0b,Wih1b,Whh1b,b_ih1,b_hh1,ey_pre,
                                attc,h0g,h1g,hdec,barcnt);

  // post GEMM + joint
  k_gemm <<<dim3(8,8),256,0,stream>>>(hdec,nullptr,512, W_lin_dec,512,0, nullptr,nullptr, 0,0, lin_dec,512, 512);
  k_joint<<<2048,256,0,stream>>>(lin_enc,lin_dec,WoT,b_out,out);
}

// Round 8
// 2797.471 us; speedup vs baseline: 2.8246x; 1.4549x over previous
//
#include <hip/hip_runtime.h>
#include <cstddef>
#include <cstdint>

typedef unsigned short u16;
typedef __attribute__((ext_vector_type(8))) unsigned short u16x8;
typedef __attribute__((ext_vector_type(8))) short s16x8;
typedef __attribute__((ext_vector_type(4))) float f32x4;

#define B_ 8
#define T_ 256
#define U_ 64
#define D_ 512
#define G_ 2048   // 4*DUNITS
#define OD 500
#define NBLK 136  // 8 attention + 128 LSTM blocks (<=256 -> co-resident)

__device__ __forceinline__ float bf2f(u16 u){ unsigned v=((unsigned)u)<<16; return __builtin_bit_cast(float,v); }
__device__ __forceinline__ u16 f2bf(float f){ unsigned u=__builtin_bit_cast(unsigned,f); u += 0x7fffu + ((u>>16)&1u); return (u16)(u>>16); }
__device__ __forceinline__ float sigm(float x){ return 1.f/(1.f+expf(-x)); }
__device__ __forceinline__ float wredsum(float v){
  #pragma unroll
  for(int o=32;o;o>>=1) v += __shfl_xor(v,o);
  return v;
}
__device__ __forceinline__ float wredmax(float v){
  #pragma unroll
  for(int o=32;o;o>>=1) v = fmaxf(v,__shfl_xor(v,o));
  return v;
}

// coherent cross-block access: relaxed agent-scope atomics execute at the LLC
// coherence point (proven correct r5-r7). No fences -> weights stay L2-hot.
__device__ __forceinline__ float gload(const float* p){
  return __hip_atomic_load(p, __ATOMIC_RELAXED, __HIP_MEMORY_SCOPE_AGENT);
}
__device__ __forceinline__ void gstore(float* p, float v){
  __hip_atomic_store(p, v, __ATOMIC_RELAXED, __HIP_MEMORY_SCOPE_AGENT);
}

// fence-free monotonic grid barrier. s_sleep(32) ~ 2k cycles poll period:
// 136 pollers on one LLC line at 0.3us period was saturating the line and
// queueing the arrival RMWs behind the reads (r7: ~15us/barrier).
__device__ __forceinline__ void gridbar(unsigned* cnt, unsigned target){
  __syncthreads();
  if(threadIdx.x==0){
    asm volatile("s_waitcnt vmcnt(0)" ::: "memory");
    __hip_atomic_fetch_add(cnt,1u,__ATOMIC_RELAXED,__HIP_MEMORY_SCOPE_AGENT);
    while(__hip_atomic_load(cnt,__ATOMIC_RELAXED,__HIP_MEMORY_SCOPE_AGENT) < target){
      __builtin_amdgcn_s_sleep(32);
    }
  }
  __syncthreads();
}

// ---------------- conversion kernels (one-time per call) ----------------
__global__ void k_f2bf(const float* __restrict__ s, u16* __restrict__ d, int n){
  int i=blockIdx.x*256+threadIdx.x; if(i<n) d[i]=f2bf(s[i]);
}
__global__ void k_trans_bf(const float* __restrict__ s, u16* __restrict__ d, int R, int C){
  int i=blockIdx.x*256+threadIdx.x; if(i>=R*C) return;
  int c=i/R, r=i-c*R; d[i]=f2bf(s[(size_t)r*C+c]);
}
__global__ void k_wi0a(const float* __restrict__ W, u16* __restrict__ d){
  int i=blockIdx.x*256+threadIdx.x; if(i>=G_*D_) return;
  int g=i>>9, e=i&511; d[i]=f2bf(W[(size_t)g*1024 + 512 + e]);
}
__global__ void k_woT(const float* __restrict__ W, u16* __restrict__ d){
  int i=blockIdx.x*256+threadIdx.x; if(i>=512*512) return;
  int o=i>>9, j=i&511; d[i] = (o<OD)? f2bf(W[(size_t)j*OD+o]) : (u16)0;
}
// peT[b][a][t] = pe_bf[b][t][a]  (coalesced-on-t layout for the e-phase)
__global__ void k_peT(const u16* __restrict__ s, u16* __restrict__ d){
  int i=blockIdx.x*256+threadIdx.x; if(i>=B_*512*T_) return;
  int t=i&255, a=(i>>8)&511, b=i>>17;
  d[i]=s[((size_t)(b*256+t))*512 + a];
}

// ---------------- generic bf16-MFMA GEMM (pre/post passes) ----------------
__global__ __launch_bounds__(256) void k_gemm(
  const float* __restrict__ A, const int* __restrict__ gidx, int lda,
  const float* __restrict__ Bm, int ldb, int bT,
  const float* __restrict__ bias1, const float* __restrict__ bias2,
  int actTanh, int outBf16, void* __restrict__ C, int ldc, int K)
{
  __shared__ __align__(16) u16 As[64][40];
  __shared__ __align__(16) u16 Bs[64][40];
  int tid=threadIdx.x;
  int m0=blockIdx.x*64, n0=blockIdx.y*64;
  int w=tid>>6, l=tid&63;
  f32x4 acc[4];
  #pragma unroll
  for(int nt=0;nt<4;++nt) acc[nt]=(f32x4){0.f,0.f,0.f,0.f};
  int arow=tid>>2, aseg=tid&3;
  int ar = gidx ? gidx[m0+arow] : (m0+arow);
  const float* Ap = A + (size_t)ar*lda + aseg*8;

  for(int kt=0;kt<K/32;++kt){
    const float* ap = Ap + kt*32;
    f32x4 a0=*(const f32x4*)ap, a1=*(const f32x4*)(ap+4);
    #pragma unroll
    for(int i=0;i<4;++i){ As[arow][aseg*8+i]=f2bf(a0[i]); As[arow][aseg*8+4+i]=f2bf(a1[i]); }
    if(bT){
      const float* bp = Bm + (size_t)(n0+arow)*ldb + kt*32 + aseg*8;
      f32x4 b0=*(const f32x4*)bp, b1=*(const f32x4*)(bp+4);
      #pragma unroll
      for(int i=0;i<4;++i){ Bs[arow][aseg*8+i]=f2bf(b0[i]); Bs[arow][aseg*8+4+i]=f2bf(b1[i]); }
    } else {
      int bk=tid>>3, bn=(tid&7)*8;
      const float* bp = Bm + (size_t)(kt*32+bk)*ldb + n0 + bn;
      f32x4 b0=*(const f32x4*)bp, b1=*(const f32x4*)(bp+4);
      #pragma unroll
      for(int i=0;i<4;++i){ Bs[bn+i][bk]=f2bf(b0[i]); Bs[bn+4+i][bk]=f2bf(b1[i]); }
    }
    __syncthreads();
    s16x8 af = *(const s16x8*)&As[w*16 + (l&15)][(l>>4)*8];
    #pragma unroll
    for(int nt=0;nt<4;++nt){
      s16x8 bf = *(const s16x8*)&Bs[nt*16 + (l&15)][(l>>4)*8];
      acc[nt]=__builtin_amdgcn_mfma_f32_16x16x32_bf16(af,bf,acc[nt],0,0,0);
    }
    __syncthreads();
  }
  int mr = w*16 + ((l>>4)<<2), cc = l&15;
  #pragma unroll
  for(int nt=0;nt<4;++nt){
    int gn = n0 + nt*16 + cc;
    float bb = (bias1?bias1[gn]:0.f) + (bias2?bias2[gn]:0.f);
    #pragma unroll
    for(int r=0;r<4;++r){
      int gm = m0 + mr + r;
      float v = acc[nt][r] + bb;
      if(actTanh) v = tanhf(v);
      if(outBf16) ((u16*)C)[(size_t)gm*ldc+gn] = f2bf(v);
      else        ((float*)C)[(size_t)gm*ldc+gn] = v;
    }
  }
}

// one 16(rows)x16(batch)xK matvec unit on MFMA (weights L2-hot, x-panel in LDS)
__device__ __forceinline__ f32x4 mfma_unit(const u16* __restrict__ Wb, const u16* xb,
                                           int lb, int l, int k0, int nks){
  int rl=l&15;
  int row = ((rl>>2)<<9) + (lb<<2) + (rl&3);
  const u16* wp = Wb + (size_t)row*512 + k0 + ((l>>4)*8);
  const u16* xp = xb + (size_t)rl*520 + k0 + ((l>>4)*8);
  f32x4 acc=(f32x4){0.f,0.f,0.f,0.f};
  for(int ks=0;ks<nks;++ks){
    s16x8 af=*(const s16x8*)(wp + ks*32);
    s16x8 bf=*(const s16x8*)(xp + ks*32);
    acc=__builtin_amdgcn_mfma_f32_16x16x32_bf16(af,bf,acc,0,0,0);
  }
  return acc;
}

// ---------------- persistent scan kernel ----------------
// 136 blocks x 256 thr, 2 grid barriers/step.
// blocks 0..7   : batch-local q -> e -> softmax -> attc (all coalesced, no
//                 cross-lane reduce in the hot loops)
// blocks 8..135 : LSTM1(u-1) + Whh0 partial on MFMA (A); LSTM0 on MFMA (B)
__global__ __launch_bounds__(256) void k_scan(
  const u16* __restrict__ WdT, const float* __restrict__ b_att_dec,
  const u16* __restrict__ peT, const u16* __restrict__ hs_bf, const int* __restrict__ hlens,
  const u16* __restrict__ Wi0a, const u16* __restrict__ Whh0b,
  const u16* __restrict__ Wih1b, const u16* __restrict__ Whh1b,
  const float* __restrict__ b_ih1, const float* __restrict__ b_hh1,
  const float* __restrict__ ey_pre,
  float* __restrict__ attc, float* __restrict__ h0g, float* __restrict__ h1g,
  float* __restrict__ hdec, unsigned* __restrict__ barcnt)
{
  __shared__ __align__(16) char smraw[38400];
  int tid=threadIdx.x, bid=blockIdx.x;
  unsigned baridx=0;

  if(bid>=8){
    int lb=bid-8, w=tid>>6, l=tid&63;
    u16*  xbf=(u16*)smraw;              // 16x520 bf16 x-panel (h0 / attc)
    u16*  hbf=(u16*)(smraw+16640);      // 16x520 bf16 h1prev
    float* gl=(float*)(smraw+33280);    // [4][16][16] C-frag dump
    float* gp=(float*)(smraw+37376);    // [16][16] Whh0 partial, survives barrier
    for(int i=tid;i<16*520;i+=256){ xbf[i]=0; hbf[i]=0; }  // cols 8..15 stay 0
    float c0r=0.f, c1r=0.f;
    int jj=(tid>>3)&3, b=tid&7;         // epilogue cell for tid<32

    for(int u=0;u<=U_;++u){
      float* h1prev=h1g+(u&1)*4096;
      float* h1new =h1g+((u+1)&1)*4096;
      // ---- phase A: stage h0,h1prev; MFMA Wih1/Whh1/Whh0; h1 epilogue ----
      for(int i=tid;i<4096;i+=256){
        int bb=i>>9,k=i&511;
        xbf[bb*520+k]=f2bf(gload(h0g+i));
        hbf[bb*520+k]=f2bf(gload(h1prev+i));
      }
      __syncthreads();
      f32x4 acc;
      if(w==0)      acc=mfma_unit(Wih1b,xbf,lb,l,0,16);
      else if(w==1) acc=mfma_unit(Whh1b,hbf,lb,l,0,16);
      else if(w==2) acc=mfma_unit(Whh0b,xbf,lb,l,0,8);
      else          acc=mfma_unit(Whh0b,xbf,lb,l,256,8);
      {
        float* gld=gl+w*256;
        #pragma unroll
        for(int r=0;r<4;++r) gld[((l>>4)*4+r)*16+(l&15)]=acc[r];
      }
      __syncthreads();
      gp[tid]=gl[512+tid]+gl[768+tid];      // Whh0 k-halves combined
      if(u>0 && tid<32){
        int j=lb*4+jj;
        float gv[4];
        #pragma unroll
        for(int g=0;g<4;++g){
          int ridx=g*4+jj, row=g*512+j;
          gv[g]=gl[ridx*16+b]+gl[256+ridx*16+b]+b_ih1[row]+b_hh1[row];
        }
        float i_=sigm(gv[0]), f_=sigm(gv[1]), g_=tanhf(gv[2]), o_=sigm(gv[3]);
        c1r=f_*c1r+i_*g_;
        float h=o_*tanhf(c1r);
        gstore(h1new+b*512+j,h);
        hdec[((size_t)(b*64+(u-1)))*512+j]=h;
      }
      if(u==U_) break;
      gridbar(barcnt,NBLK*(++baridx));

      // ---- phase B: LSTM0 = ey + gpart + Wi0a*attc ----
      for(int i=tid;i<4096;i+=256){ int bb=i>>9,k=i&511; xbf[bb*520+k]=f2bf(gload(attc+i)); }
      __syncthreads();
      acc=mfma_unit(Wi0a,xbf,lb,l,w*128,4);
      {
        float* gld=gl+w*256;
        #pragma unroll
        for(int r=0;r<4;++r) gld[((l>>4)*4+r)*16+(l&15)]=acc[r];
      }
      __syncthreads();
      if(tid<32){
        int j=lb*4+jj;
        float gv[4];
        #pragma unroll
        for(int g=0;g<4;++g){
          int ridx=g*4+jj, row=g*512+j;
          gv[g]=gl[ridx*16+b]+gl[256+ridx*16+b]+gl[512+ridx*16+b]+gl[768+ridx*16+b]
               +gp[ridx*16+b]+ey_pre[((size_t)((b<<6)|u))*2048+row];
        }
        float i_=sigm(gv[0]), f_=sigm(gv[1]), g_=tanhf(gv[2]), o_=sigm(gv[3]);
        c0r=f_*c0r+i_*g_;
        gstore(h0g+b*512+j,o_*tanhf(c0r));
      }
      gridbar(barcnt,NBLK*(++baridx));
    }
  } else {
    // ---- attention block, batch b ----
    int b=bid;
    float* h0s=(float*)smraw;            // 512 f
    float* qs =(float*)(smraw+2048);     // 512 f
    float* ew =(float*)(smraw+4096);     // 256 f
    float* red=(float*)(smraw+5120);     // 16 f
    int wv=tid>>6, ln=tid&63;
    int hl=hlens[b];
    for(int u=0;u<=U_;++u){
      if(u<U_){
        for(int i=tid;i<512;i+=256) h0s[i]=gload(h0g+b*512+i);
        __syncthreads();
        // q = tanh(WdT @ h0 + b): 2 rows/thread, no cross-lane ops
        #pragma unroll
        for(int rep=0;rep<2;++rep){
          int a_=tid+rep*256;
          const u16* wr=WdT+(size_t)a_*512;
          float p0=0.f,p1=0.f,p2=0.f,p3=0.f;
          for(int kc=0;kc<64;++kc){
            u16x8 v=*(const u16x8*)(wr+kc*8);
            f32x4 xa=*(const f32x4*)(h0s+kc*8), xb2=*(const f32x4*)(h0s+kc*8+4);
            p0+=bf2f(v[0])*xa[0]+bf2f(v[2])*xa[2];
            p1+=bf2f(v[1])*xa[1]+bf2f(v[3])*xa[3];
            p2+=bf2f(v[4])*xb2[0]+bf2f(v[6])*xb2[2];
            p3+=bf2f(v[5])*xb2[1]+bf2f(v[7])*xb2[3];
          }
          qs[a_]=tanhf((p0+p1)+(p2+p3)+b_att_dec[a_]);
        }
        __syncthreads();
        // e[t=tid] = peT[b][:,t].q  -- lanes read consecutive t: coalesced,
        // accumulator in-register, zero shuffles
        {
          const u16* pT=peT+(size_t)b*512*256 + tid;
          float e0=0.f,e1=0.f,e2=0.f,e3=0.f;
          for(int a=0;a<512;a+=4){
            f32x4 q4=*(const f32x4*)(qs+a);
            e0+=q4[0]*bf2f(pT[(size_t)(a  )*256]);
            e1+=q4[1]*bf2f(pT[(size_t)(a+1)*256]);
            e2+=q4[2]*bf2f(pT[(size_t)(a+2)*256]);
            e3+=q4[3]*bf2f(pT[(size_t)(a+3)*256]);
          }
          ew[tid]=(tid<hl)? (e0+e1)+(e2+e3) : -1e30f;
        }
        __syncthreads();
        float val=ew[tid];
        float m=wredmax(val);
        if(ln==0) red[wv]=m;
        __syncthreads();
        float M=fmaxf(fmaxf(red[0],red[1]),fmaxf(red[2],red[3]));
        float p=expf(val-M);
        float s=wredsum(p);
        if(ln==0) red[4+wv]=s;
        __syncthreads();
        float S=red[4]+red[5]+red[6]+red[7];
        ew[tid]=p/S;
        __syncthreads();
        // attc[2tid,2tid+1] = sum_t w[t]*hs[b][t][d] -- u32 loads, coalesced
        {
          int d0=tid*2;
          const u16* hp=hs_bf+(size_t)b*256*512 + d0;
          float a0=0.f,a1=0.f,b0=0.f,b1=0.f;
          for(int t=0;t<256;t+=2){
            unsigned v0=*(const unsigned*)(hp+(size_t)t*512);
            unsigned v1=*(const unsigned*)(hp+(size_t)(t+1)*512);
            float w0=ew[t], w1=ew[t+1];
            a0+=w0*bf2f((u16)(v0&0xffffu)); a1+=w0*bf2f((u16)(v0>>16));
            b0+=w1*bf2f((u16)(v1&0xffffu)); b1+=w1*bf2f((u16)(v1>>16));
          }
          gstore(attc+b*512+d0,   a0+b0);
          gstore(attc+b*512+d0+1, a1+b1);
        }
      }
      if(u==U_) break;
      gridbar(barcnt,NBLK*(++baridx));
      gridbar(barcnt,NBLK*(++baridx));
    }
  }
}

// ---------------- joint network ----------------
// 32-row t-tiles (33KB LDS -> 2 blocks/CU for latency hiding)
__global__ __launch_bounds__(256) void k_joint(
  const float* __restrict__ lin_enc, const float* __restrict__ lin_dec,
  const u16* __restrict__ WoT, const float* __restrict__ b_out,
  float* __restrict__ out)
{
  __shared__ __align__(16) u16 As[32*512];
  __shared__ float ld_s[512];
  int tid=threadIdx.x, bid=blockIdx.x;
  int b=bid>>9, u=(bid>>3)&63, t0=(bid&7)*32;
  for(int i=tid;i<512;i+=256) ld_s[i]=lin_dec[((size_t)((b<<6)|u))*512 + i];
  __syncthreads();
  const float* le = lin_enc + ((size_t)(b*256 + t0))*512;
  for(int it=0;it<8;++it){
    int idx=it*256+tid;
    int row=idx>>6, c0=(idx&63)*8;
    f32x4 x0=*(const f32x4*)(le + (size_t)row*512 + c0);
    f32x4 x1=*(const f32x4*)(le + (size_t)row*512 + c0 + 4);
    u16x8 pk;
    #pragma unroll
    for(int i=0;i<4;++i){
      pk[i]  =f2bf(tanhf(x0[i]+ld_s[c0+i]));
      pk[4+i]=f2bf(tanhf(x1[i]+ld_s[c0+4+i]));
    }
    int sc = c0 ^ ((row&7)<<3);
    *(u16x8*)&As[row*512+sc]=pk;
  }
  __syncthreads();
  int w=tid>>6, l=tid&63;
  for(int ch=0;ch<8;++ch){
    int n0=ch*64 + w*16;
    int o = n0 + (l&15);
    s16x8 bfr[16];
    const u16* wp = WoT + (size_t)o*512 + ((l>>4)*8);
    #pragma unroll
    for(int ks=0;ks<16;++ks) bfr[ks]=*(const s16x8*)(wp + ks*32);
    float bo = (o<OD)? b_out[o] : 0.f;
    #pragma unroll
    for(int mt=0;mt<2;++mt){
      f32x4 acc=(f32x4){0.f,0.f,0.f,0.f};
      int row = mt*16 + (l&15);
      int sw  = (row&7)<<3;
      #pragma unroll
      for(int ks=0;ks<16;++ks){
        int cidx=(ks*32 + (l>>4)*8) ^ sw;
        s16x8 af=*(const s16x8*)&As[row*512+cidx];
        acc=__builtin_amdgcn_mfma_f32_16x16x32_bf16(af,bfr[ks],acc,0,0,0);
      }
      if(o<OD){
        #pragma unroll
        for(int r=0;r<4;++r){
          int t = t0 + mt*16 + ((l>>4)<<2) + r;
          out[(((size_t)(b*256+t))*64 + u)*500 + o] = acc[r] + bo;
        }
      }
    }
  }
}

// ---------------- host launcher ----------------
extern "C" void kernel_launch(void* const* d_in, const int* in_sizes, int n_in,
                              void* d_out, int out_size, void* d_ws, size_t ws_size,
                              hipStream_t stream)
{
  (void)in_sizes; (void)n_in; (void)out_size; (void)ws_size;
  const float* hs_pad   =(const float*)d_in[0];
  const int*   ys       =(const int*)  d_in[1];
  const int*   hlens    =(const int*)  d_in[2];
  const float* emb      =(const float*)d_in[3];
  const float* W_ih0    =(const float*)d_in[4];
  const float* W_hh0    =(const float*)d_in[5];
  const float* b_ih0    =(const float*)d_in[6];
  const float* b_hh0    =(const float*)d_in[7];
  const float* W_ih1    =(const float*)d_in[8];
  const float* W_hh1    =(const float*)d_in[9];
  const float* b_ih1    =(const float*)d_in[10];
  const float* b_hh1    =(const float*)d_in[11];
  const float* W_att_enc=(const float*)d_in[12];
  const float* b_att_enc=(const float*)d_in[13];
  const float* W_att_dec=(const float*)d_in[14];
  const float* b_att_dec=(const float*)d_in[15];
  const float* W_lin_enc=(const float*)d_in[16];
  const float* b_lin_enc=(const float*)d_in[17];
  const float* W_lin_dec=(const float*)d_in[18];
  const float* W_out    =(const float*)d_in[19];
  const float* b_out    =(const float*)d_in[20];
  float* out=(float*)d_out;

  char* wp=(char*)d_ws;
  auto carve=[&](size_t bytes)->char*{ char* p=wp; wp += (bytes+255)&~(size_t)255; return p; };
  u16*   hs_bf  =(u16*)  carve((size_t)B_*T_*D_*2);
  u16*   pe_bf  =(u16*)  carve((size_t)B_*T_*D_*2);
  u16*   peT    =(u16*)  carve((size_t)B_*D_*T_*2);
  u16*   WdT    =(u16*)  carve((size_t)512*512*2);
  u16*   Wi0a   =(u16*)  carve((size_t)G_*512*2);
  u16*   Whh0b  =(u16*)  carve((size_t)G_*512*2);
  u16*   Wih1b  =(u16*)  carve((size_t)G_*512*2);
  u16*   Whh1b  =(u16*)  carve((size_t)G_*512*2);
  u16*   WoT    =(u16*)  carve((size_t)512*512*2);
  float* lin_enc=(float*)carve((size_t)B_*T_*512*4);
  float* ey_pre =(float*)carve((size_t)B_*U_*G_*4);
  float* hdec   =(float*)carve((size_t)B_*U_*512*4);
  float* lin_dec=(float*)carve((size_t)B_*U_*512*4);
  float* attc   =(float*)carve(4096*4);
  float* states =(float*)carve(3*4096*4);
  unsigned* barcnt=(unsigned*)carve(256);
  float* h0g=states;            // 4096
  float* h1g=states+4096;       // 2 x 4096 (ping-pong)

  hipMemsetAsync(states,0,3*4096*4,stream);
  hipMemsetAsync(barcnt,0,256,stream);

  int n1=B_*T_*D_, n2=G_*512;
  k_f2bf    <<<(n1+255)/256,256,0,stream>>>(hs_pad,hs_bf,n1);
  k_trans_bf<<<(512*512+255)/256,256,0,stream>>>(W_att_dec,WdT,512,512);
  k_wi0a    <<<(n2+255)/256,256,0,stream>>>(W_ih0,Wi0a);
  k_f2bf    <<<(n2+255)/256,256,0,stream>>>(W_hh0,Whh0b,n2);
  k_f2bf    <<<(n2+255)/256,256,0,stream>>>(W_ih1,Wih1b,n2);
  k_f2bf    <<<(n2+255)/256,256,0,stream>>>(W_hh1,Whh1b,n2);
  k_woT     <<<(512*512+255)/256,256,0,stream>>>(W_out,WoT);

  // pre GEMMs
  k_gemm<<<dim3(32,8),256,0,stream>>>(hs_pad,nullptr,512, W_att_enc,512,0, b_att_enc,nullptr, 1,1, pe_bf,512, 512);
  k_peT <<<(B_*512*T_+255)/256,256,0,stream>>>(pe_bf,peT);
  k_gemm<<<dim3(32,8),256,0,stream>>>(hs_pad,nullptr,512, W_lin_enc,512,0, b_lin_enc,nullptr, 0,0, lin_enc,512, 512);
  k_gemm<<<dim3(8,32),256,0,stream>>>(emb,ys,512,        W_ih0,1024,1,    b_ih0,b_hh0,      0,0, ey_pre,2048, 512);

  // persistent scan: one launch for all 64 steps
  k_scan<<<NBLK,256,0,stream>>>(WdT,b_att_dec,peT,hs_bf,hlens,
                                Wi0a,Whh0b,Wih1b,Whh1b,b_ih1,b_hh1,ey_pre,
                                attc,h0g,h1g,hdec,barcnt);

  // post GEMM + joint
  k_gemm <<<dim3(8,8),256,0,stream>>>(hdec,nullptr,512, W_lin_dec,512,0, nullptr,nullptr, 0,0, lin_dec,512, 512);
  k_joint<<<4096,256,0,stream>>>(lin_enc,lin_dec,WoT,b_out,out);
}

// Round 9
// 2176.314 us; speedup vs baseline: 3.6308x; 1.2854x over previous
//
#include <hip/hip_runtime.h>
#include <cstddef>
#include <cstdint>

typedef unsigned short u16;
typedef __attribute__((ext_vector_type(8))) unsigned short u16x8;
typedef __attribute__((ext_vector_type(8))) short s16x8;
typedef __attribute__((ext_vector_type(4))) float f32x4;

#define B_ 8
#define T_ 256
#define U_ 64
#define D_ 512
#define G_ 2048   // 4*DUNITS
#define OD 500
#define NBLK 192  // 128 LSTM + 64 attention blocks (<=256 -> co-resident)

__device__ __forceinline__ float bf2f(u16 u){ unsigned v=((unsigned)u)<<16; return __builtin_bit_cast(float,v); }
__device__ __forceinline__ u16 f2bf(float f){ unsigned u=__builtin_bit_cast(unsigned,f); u += 0x7fffu + ((u>>16)&1u); return (u16)(u>>16); }
__device__ __forceinline__ float sigm(float x){ return 1.f/(1.f+expf(-x)); }
__device__ __forceinline__ float wredsum(float v){
  #pragma unroll
  for(int o=32;o;o>>=1) v += __shfl_xor(v,o);
  return v;
}
__device__ __forceinline__ float wredmax(float v){
  #pragma unroll
  for(int o=32;o;o>>=1) v = fmaxf(v,__shfl_xor(v,o));
  return v;
}

// coherent cross-block access: relaxed agent-scope atomics execute at the LLC
// coherence point (proven correct r5-r8). No fences -> weights stay L2-hot.
__device__ __forceinline__ float gload(const float* p){
  return __hip_atomic_load(p, __ATOMIC_RELAXED, __HIP_MEMORY_SCOPE_AGENT);
}
__device__ __forceinline__ void gstore(float* p, float v){
  __hip_atomic_store(p, v, __ATOMIC_RELAXED, __HIP_MEMORY_SCOPE_AGENT);
}

// hierarchical fence-free grid barrier: 6 arrival counters on separate 128B
// lines (32 RMWs each, parallel LLC slices) + leader-released epoch flag.
// r8's flat single-line barrier serialized 136 RMWs (~2-3us/barrier).
__device__ __forceinline__ void gridbar(unsigned* bar, int bid, unsigned gen){
  __syncthreads();
  if(threadIdx.x==0){
    asm volatile("s_waitcnt vmcnt(0)" ::: "memory");
    __hip_atomic_fetch_add(bar+((bid>>5)<<5),1u,__ATOMIC_RELAXED,__HIP_MEMORY_SCOPE_AGENT);
    if(bid==0){
      #pragma unroll 1
      for(int g=0;g<6;++g){
        while(__hip_atomic_load(bar+(g<<5),__ATOMIC_RELAXED,__HIP_MEMORY_SCOPE_AGENT) < 32u*gen)
          __builtin_amdgcn_s_sleep(8);
      }
      __hip_atomic_store(bar+192,gen,__ATOMIC_RELAXED,__HIP_MEMORY_SCOPE_AGENT);
    } else {
      while(__hip_atomic_load(bar+192,__ATOMIC_RELAXED,__HIP_MEMORY_SCOPE_AGENT) < gen)
        __builtin_amdgcn_s_sleep(16);
    }
  }
  __syncthreads();
}

// ---------------- conversion kernels (one-time per call) ----------------
__global__ void k_f2bf(const float* __restrict__ s, u16* __restrict__ d, int n){
  int i=blockIdx.x*256+threadIdx.x; if(i<n) d[i]=f2bf(s[i]);
}
__global__ void k_trans_bf(const float* __restrict__ s, u16* __restrict__ d, int R, int C){
  int i=blockIdx.x*256+threadIdx.x; if(i>=R*C) return;
  int c=i/R, r=i-c*R; d[i]=f2bf(s[(size_t)r*C+c]);
}
__global__ void k_wi0a(const float* __restrict__ W, u16* __restrict__ d){
  int i=blockIdx.x*256+threadIdx.x; if(i>=G_*D_) return;
  int g=i>>9, e=i&511; d[i]=f2bf(W[(size_t)g*1024 + 512 + e]);
}
__global__ void k_woT(const float* __restrict__ W, u16* __restrict__ d){
  int i=blockIdx.x*256+threadIdx.x; if(i>=512*512) return;
  int o=i>>9, j=i&511; d[i] = (o<OD)? f2bf(W[(size_t)j*OD+o]) : (u16)0;
}
// peT[b][a][t] = pe_bf[b][t][a]  (coalesced-on-t layout for the e-phase)
__global__ void k_peT(const u16* __restrict__ s, u16* __restrict__ d){
  int i=blockIdx.x*256+threadIdx.x; if(i>=B_*512*T_) return;
  int t=i&255, a=(i>>8)&511, b=i>>17;
  d[i]=s[((size_t)(b*256+t))*512 + a];
}

// ---------------- generic bf16-MFMA GEMM (pre/post passes) ----------------
__global__ __launch_bounds__(256) void k_gemm(
  const float* __restrict__ A, const int* __restrict__ gidx, int lda,
  const float* __restrict__ Bm, int ldb, int bT,
  const float* __restrict__ bias1, const float* __restrict__ bias2,
  int actTanh, int outBf16, void* __restrict__ C, int ldc, int K)
{
  __shared__ __align__(16) u16 As[64][40];
  __shared__ __align__(16) u16 Bs[64][40];
  int tid=threadIdx.x;
  int m0=blockIdx.x*64, n0=blockIdx.y*64;
  int w=tid>>6, l=tid&63;
  f32x4 acc[4];
  #pragma unroll
  for(int nt=0;nt<4;++nt) acc[nt]=(f32x4){0.f,0.f,0.f,0.f};
  int arow=tid>>2, aseg=tid&3;
  int ar = gidx ? gidx[m0+arow] : (m0+arow);
  const float* Ap = A + (size_t)ar*lda + aseg*8;

  for(int kt=0;kt<K/32;++kt){
    const float* ap = Ap + kt*32;
    f32x4 a0=*(const f32x4*)ap, a1=*(const f32x4*)(ap+4);
    #pragma unroll
    for(int i=0;i<4;++i){ As[arow][aseg*8+i]=f2bf(a0[i]); As[arow][aseg*8+4+i]=f2bf(a1[i]); }
    if(bT){
      const float* bp = Bm + (size_t)(n0+arow)*ldb + kt*32 + aseg*8;
      f32x4 b0=*(const f32x4*)bp, b1=*(const f32x4*)(bp+4);
      #pragma unroll
      for(int i=0;i<4;++i){ Bs[arow][aseg*8+i]=f2bf(b0[i]); Bs[arow][aseg*8+4+i]=f2bf(b1[i]); }
    } else {
      int bk=tid>>3, bn=(tid&7)*8;
      const float* bp = Bm + (size_t)(kt*32+bk)*ldb + n0 + bn;
      f32x4 b0=*(const f32x4*)bp, b1=*(const f32x4*)(bp+4);
      #pragma unroll
      for(int i=0;i<4;++i){ Bs[bn+i][bk]=f2bf(b0[i]); Bs[bn+4+i][bk]=f2bf(b1[i]); }
    }
    __syncthreads();
    s16x8 af = *(const s16x8*)&As[w*16 + (l&15)][(l>>4)*8];
    #pragma unroll
    for(int nt=0;nt<4;++nt){
      s16x8 bf = *(const s16x8*)&Bs[nt*16 + (l&15)][(l>>4)*8];
      acc[nt]=__builtin_amdgcn_mfma_f32_16x16x32_bf16(af,bf,acc[nt],0,0,0);
    }
    __syncthreads();
  }
  int mr = w*16 + ((l>>4)<<2), cc = l&15;
  #pragma unroll
  for(int nt=0;nt<4;++nt){
    int gn = n0 + nt*16 + cc;
    float bb = (bias1?bias1[gn]:0.f) + (bias2?bias2[gn]:0.f);
    #pragma unroll
    for(int r=0;r<4;++r){
      int gm = m0 + mr + r;
      float v = acc[nt][r] + bb;
      if(actTanh) v = tanhf(v);
      if(outBf16) ((u16*)C)[(size_t)gm*ldc+gn] = f2bf(v);
      else        ((float*)C)[(size_t)gm*ldc+gn] = v;
    }
  }
}

// one 16(rows)x16(batch)xK matvec unit on MFMA (weights L2-hot, x-panel in LDS)
__device__ __forceinline__ f32x4 mfma_unit(const u16* __restrict__ Wb, const u16* xb,
                                           int lb, int l, int k0, int nks){
  int rl=l&15;
  int row = ((rl>>2)<<9) + (lb<<2) + (rl&3);
  const u16* wp = Wb + (size_t)row*512 + k0 + ((l>>4)*8);
  const u16* xp = xb + (size_t)rl*520 + k0 + ((l>>4)*8);
  f32x4 acc=(f32x4){0.f,0.f,0.f,0.f};
  for(int ks=0;ks<nks;++ks){
    s16x8 af=*(const s16x8*)(wp + ks*32);
    s16x8 bf=*(const s16x8*)(xp + ks*32);
    acc=__builtin_amdgcn_mfma_f32_16x16x32_bf16(af,bf,acc,0,0,0);
  }
  return acc;
}

// ---------------- persistent scan kernel ----------------
// 192 blocks x 256 thr, 3 grid barriers/step, every phase wide:
//  X: LSTM blocks 0..127: LSTM1(u-1)+Whh0 on MFMA | attn blocks 128..191
//     (b, a-chunk): q-chunk + e-partials (each block's WdT/peT slice L2-hot)
//  Y: attn blocks (b, d-chunk): combine e-partials, exact softmax, attc
//  Z: LSTM blocks: LSTM0 on MFMA from attc
__global__ __launch_bounds__(256) void k_scan(
  const u16* __restrict__ WdT, const float* __restrict__ b_att_dec,
  const u16* __restrict__ peT, const u16* __restrict__ hs_bf, const int* __restrict__ hlens,
  const u16* __restrict__ Wi0a, const u16* __restrict__ Whh0b,
  const u16* __restrict__ Wih1b, const u16* __restrict__ Whh1b,
  const float* __restrict__ b_ih1, const float* __restrict__ b_hh1,
  const float* __restrict__ ey_pre, float* __restrict__ e_part,
  float* __restrict__ attc, float* __restrict__ h0g, float* __restrict__ h1g,
  float* __restrict__ hdec, unsigned* __restrict__ barcnt)
{
  __shared__ __align__(16) char smraw[38400];
  int tid=threadIdx.x, bid=blockIdx.x;
  unsigned baridx=0;

  if(bid<128){
    int lb=bid, w=tid>>6, l=tid&63;
    u16*  xbf=(u16*)smraw;              // 16x520 bf16 x-panel (h0 / attc)
    u16*  hbf=(u16*)(smraw+16640);      // 16x520 bf16 h1prev
    float* gl=(float*)(smraw+33280);    // [4][16][16] C-frag dump
    float* gp=(float*)(smraw+37376);    // [16][16] Whh0 partial, survives barriers
    for(int i=tid;i<16*520;i+=256){ xbf[i]=0; hbf[i]=0; }  // cols 8..15 stay 0
    float c0r=0.f, c1r=0.f;
    int jj=(tid>>3)&3, b=tid&7;         // epilogue cell for tid<32

    for(int u=0;u<=U_;++u){
      float* h1prev=h1g+(u&1)*4096;
      float* h1new =h1g+((u+1)&1)*4096;
      // ---- X ----
      for(int i=tid;i<4096;i+=256){
        int bb=i>>9,kk=i&511;
        xbf[bb*520+kk]=f2bf(gload(h0g+i));
        hbf[bb*520+kk]=f2bf(gload(h1prev+i));
      }
      __syncthreads();
      f32x4 acc;
      if(w==0)      acc=mfma_unit(Wih1b,xbf,lb,l,0,16);
      else if(w==1) acc=mfma_unit(Whh1b,hbf,lb,l,0,16);
      else if(w==2) acc=mfma_unit(Whh0b,xbf,lb,l,0,8);
      else          acc=mfma_unit(Whh0b,xbf,lb,l,256,8);
      {
        float* gld=gl+w*256;
        #pragma unroll
        for(int r=0;r<4;++r) gld[((l>>4)*4+r)*16+(l&15)]=acc[r];
      }
      __syncthreads();
      gp[tid]=gl[512+tid]+gl[768+tid];      // Whh0 k-halves combined
      if(u>0 && tid<32){
        int j=lb*4+jj;
        float gv[4];
        #pragma unroll
        for(int g=0;g<4;++g){
          int ridx=g*4+jj, row=g*512+j;
          gv[g]=gl[ridx*16+b]+gl[256+ridx*16+b]+b_ih1[row]+b_hh1[row];
        }
        float i_=sigm(gv[0]), f_=sigm(gv[1]), g_=tanhf(gv[2]), o_=sigm(gv[3]);
        c1r=f_*c1r+i_*g_;
        float h=o_*tanhf(c1r);
        gstore(h1new+b*512+j,h);
        hdec[((size_t)(b*64+(u-1)))*512+j]=h;
      }
      if(u==U_) break;
      gridbar(barcnt,bid,++baridx);   // X -> Y
      gridbar(barcnt,bid,++baridx);   // Y -> Z (LSTM idle in Y)
      // ---- Z: LSTM0 = ey + gpart + Wi0a*attc ----
      for(int i=tid;i<4096;i+=256){ int bb=i>>9,kk=i&511; xbf[bb*520+kk]=f2bf(gload(attc+i)); }
      __syncthreads();
      acc=mfma_unit(Wi0a,xbf,lb,l,w*128,4);
      {
        float* gld=gl+w*256;
        #pragma unroll
        for(int r=0;r<4;++r) gld[((l>>4)*4+r)*16+(l&15)]=acc[r];
      }
      __syncthreads();
      if(tid<32){
        int j=lb*4+jj;
        float gv[4];
        #pragma unroll
        for(int g=0;g<4;++g){
          int ridx=g*4+jj, row=g*512+j;
          gv[g]=gl[ridx*16+b]+gl[256+ridx*16+b]+gl[512+ridx*16+b]+gl[768+ridx*16+b]
               +gp[ridx*16+b]+ey_pre[((size_t)((b<<6)|u))*2048+row];
        }
        float i_=sigm(gv[0]), f_=sigm(gv[1]), g_=tanhf(gv[2]), o_=sigm(gv[3]);
        c0r=f_*c0r+i_*g_;
        gstore(h0g+b*512+j,o_*tanhf(c0r));
      }
      gridbar(barcnt,bid,++baridx);   // Z -> next X
    }
  } else {
    // ---- attention block: batch b, chunk c (a-chunk in X, d-chunk in Y) ----
    int k=bid-128, b=k>>3, c=k&7;
    float* h0s  =(float*)smraw;          // 512
    float* qpart=(float*)(smraw+2048);   // 256
    float* qs   =(float*)(smraw+3072);   // 64
    float* ew   =(float*)(smraw+3328);   // 256
    float* red  =(float*)(smraw+4352);   // 16
    float* apart=(float*)(smraw+4416);   // 256
    int wv=tid>>6, ln=tid&63;
    int hl=hlens[b];
    for(int u=0;u<=U_;++u){
      if(u<U_){
        // ---- X: q-chunk (64 a's, K split 4-way) + e-partials ----
        for(int i=tid;i<512;i+=256) h0s[i]=gload(h0g+b*512+i);
        __syncthreads();
        {
          int al=tid&63, ks=tid>>6;
          const u16* wr=WdT+(size_t)(c*64+al)*512 + ks*128;
          const float* xr=h0s+ks*128;
          float p0=0.f,p1=0.f,p2=0.f,p3=0.f;
          for(int kc=0;kc<16;++kc){
            u16x8 v=*(const u16x8*)(wr+kc*8);
            f32x4 xa=*(const f32x4*)(xr+kc*8), xb2=*(const f32x4*)(xr+kc*8+4);
            p0+=bf2f(v[0])*xa[0]+bf2f(v[2])*xa[2];
            p1+=bf2f(v[1])*xa[1]+bf2f(v[3])*xa[3];
            p2+=bf2f(v[4])*xb2[0]+bf2f(v[6])*xb2[2];
            p3+=bf2f(v[5])*xb2[1]+bf2f(v[7])*xb2[3];
          }
          qpart[(tid>>6)*64+al]=(p0+p1)+(p2+p3);
        }
        __syncthreads();
        if(tid<64) qs[tid]=tanhf(qpart[tid]+qpart[64+tid]+qpart[128+tid]+qpart[192+tid]
                                 +b_att_dec[c*64+tid]);
        __syncthreads();
        {
          // e_part[c][b][t=tid] over this block's 64 a's (lanes t-consecutive)
          const u16* pT=peT+(size_t)b*131072 + (size_t)(c*64)*256 + tid;
          float e0=0.f,e1=0.f,e2=0.f,e3=0.f;
          for(int j=0;j<64;j+=4){
            f32x4 q4=*(const f32x4*)(qs+j);
            e0+=q4[0]*bf2f(pT[(size_t)(j  )*256]);
            e1+=q4[1]*bf2f(pT[(size_t)(j+1)*256]);
            e2+=q4[2]*bf2f(pT[(size_t)(j+2)*256]);
            e3+=q4[3]*bf2f(pT[(size_t)(j+3)*256]);
          }
          gstore(e_part+(size_t)(c*8+b)*256+tid,(e0+e1)+(e2+e3));
        }
      }
      if(u==U_) break;
      gridbar(barcnt,bid,++baridx);   // X -> Y
      // ---- Y: combine e-partials, exact softmax, attc d-chunk ----
      {
        float ev=0.f;
        #pragma unroll
        for(int cc=0;cc<8;++cc) ev+=gload(e_part+(size_t)(cc*8+b)*256+tid);
        float val=(tid<hl)? ev : -1e30f;
        float m=wredmax(val);
        if(ln==0) red[wv]=m;
        __syncthreads();
        float M=fmaxf(fmaxf(red[0],red[1]),fmaxf(red[2],red[3]));
        float p=expf(val-M);
        float s=wredsum(p);
        if(ln==0) red[4+wv]=s;
        __syncthreads();
        float S=red[4]+red[5]+red[6]+red[7];
        ew[tid]=p;
        __syncthreads();
        int dl=tid&63, ts=tid>>6;
        const u16* hp=hs_bf+(size_t)b*131072 + (size_t)(ts*64)*512 + c*64 + dl;
        const float* ep=ew+ts*64;
        float a0=0.f,a1=0.f,a2=0.f,a3=0.f;
        for(int tt=0;tt<64;tt+=4){
          a0+=ep[tt  ]*bf2f(hp[(size_t)(tt  )*512]);
          a1+=ep[tt+1]*bf2f(hp[(size_t)(tt+1)*512]);
          a2+=ep[tt+2]*bf2f(hp[(size_t)(tt+2)*512]);
          a3+=ep[tt+3]*bf2f(hp[(size_t)(tt+3)*512]);
        }
        apart[ts*64+dl]=(a0+a1)+(a2+a3);
        __syncthreads();
        if(tid<64){
          float rS=1.f/S;
          gstore(attc+b*512+c*64+tid,
                 (apart[tid]+apart[64+tid]+apart[128+tid]+apart[192+tid])*rS);
        }
      }
      gridbar(barcnt,bid,++baridx);   // Y -> Z
      gridbar(barcnt,bid,++baridx);   // Z -> next X (attn idle in Z)
    }
  }
}

// ---------------- joint network ----------------
// 32-row t-tiles (33KB LDS -> 2 blocks/CU for latency hiding)
__global__ __launch_bounds__(256) void k_joint(
  const float* __restrict__ lin_enc, const float* __restrict__ lin_dec,
  const u16* __restrict__ WoT, const float* __restrict__ b_out,
  float* __restrict__ out)
{
  __shared__ __align__(16) u16 As[32*512];
  __shared__ float ld_s[512];
  int tid=threadIdx.x, bid=blockIdx.x;
  int b=bid>>9, u=(bid>>3)&63, t0=(bid&7)*32;
  for(int i=tid;i<512;i+=256) ld_s[i]=lin_dec[((size_t)((b<<6)|u))*512 + i];
  __syncthreads();
  const float* le = lin_enc + ((size_t)(b*256 + t0))*512;
  for(int it=0;it<8;++it){
    int idx=it*256+tid;
    int row=idx>>6, c0=(idx&63)*8;
    f32x4 x0=*(const f32x4*)(le + (size_t)row*512 + c0);
    f32x4 x1=*(const f32x4*)(le + (size_t)row*512 + c0 + 4);
    u16x8 pk;
    #pragma unroll
    for(int i=0;i<4;++i){
      pk[i]  =f2bf(tanhf(x0[i]+ld_s[c0+i]));
      pk[4+i]=f2bf(tanhf(x1[i]+ld_s[c0+4+i]));
    }
    int sc = c0 ^ ((row&7)<<3);
    *(u16x8*)&As[row*512+sc]=pk;
  }
  __syncthreads();
  int w=tid>>6, l=tid&63;
  for(int ch=0;ch<8;++ch){
    int n0=ch*64 + w*16;
    int o = n0 + (l&15);
    s16x8 bfr[16];
    const u16* wp = WoT + (size_t)o*512 + ((l>>4)*8);
    #pragma unroll
    for(int ks=0;ks<16;++ks) bfr[ks]=*(const s16x8*)(wp + ks*32);
    float bo = (o<OD)? b_out[o] : 0.f;
    #pragma unroll
    for(int mt=0;mt<2;++mt){
      f32x4 acc=(f32x4){0.f,0.f,0.f,0.f};
      int row = mt*16 + (l&15);
      int sw  = (row&7)<<3;
      #pragma unroll
      for(int ks=0;ks<16;++ks){
        int cidx=(ks*32 + (l>>4)*8) ^ sw;
        s16x8 af=*(const s16x8*)&As[row*512+cidx];
        acc=__builtin_amdgcn_mfma_f32_16x16x32_bf16(af,bfr[ks],acc,0,0,0);
      }
      if(o<OD){
        #pragma unroll
        for(int r=0;r<4;++r){
          int t = t0 + mt*16 + ((l>>4)<<2) + r;
          out[(((size_t)(b*256+t))*64 + u)*500 + o] = acc[r] + bo;
        }
      }
    }
  }
}

// ---------------- host launcher ----------------
extern "C" void kernel_launch(void* const* d_in, const int* in_sizes, int n_in,
                              void* d_out, int out_size, void* d_ws, size_t ws_size,
                              hipStream_t stream)
{
  (void)in_sizes; (void)n_in; (void)out_size; (void)ws_size;
  const float* hs_pad   =(const float*)d_in[0];
  const int*   ys       =(const int*)  d_in[1];
  const int*   hlens    =(const int*)  d_in[2];
  const float* emb      =(const float*)d_in[3];
  const float* W_ih0    =(const float*)d_in[4];
  const float* W_hh0    =(const float*)d_in[5];
  const float* b_ih0    =(const float*)d_in[6];
  const float* b_hh0    =(const float*)d_in[7];
  const float* W_ih1    =(const float*)d_in[8];
  const float* W_hh1    =(const float*)d_in[9];
  const float* b_ih1    =(const float*)d_in[10];
  const float* b_hh1    =(const float*)d_in[11];
  const float* W_att_enc=(const float*)d_in[12];
  const float* b_att_enc=(const float*)d_in[13];
  const float* W_att_dec=(const float*)d_in[14];
  const float* b_att_dec=(const float*)d_in[15];
  const float* W_lin_enc=(const float*)d_in[16];
  const float* b_lin_enc=(const float*)d_in[17];
  const float* W_lin_dec=(const float*)d_in[18];
  const float* W_out    =(const float*)d_in[19];
  const float* b_out    =(const float*)d_in[20];
  float* out=(float*)d_out;

  char* wp=(char*)d_ws;
  auto carve=[&](size_t bytes)->char*{ char* p=wp; wp += (bytes+255)&~(size_t)255; return p; };
  u16*   hs_bf  =(u16*)  carve((size_t)B_*T_*D_*2);
  u16*   pe_bf  =(u16*)  carve((size_t)B_*T_*D_*2);
  u16*   peT    =(u16*)  carve((size_t)B_*D_*T_*2);
  u16*   WdT    =(u16*)  carve((size_t)512*512*2);
  u16*   Wi0a   =(u16*)  carve((size_t)G_*512*2);
  u16*   Whh0b  =(u16*)  carve((size_t)G_*512*2);
  u16*   Wih1b  =(u16*)  carve((size_t)G_*512*2);
  u16*   Whh1b  =(u16*)  carve((size_t)G_*512*2);
  u16*   WoT    =(u16*)  carve((size_t)512*512*2);
  float* lin_enc=(float*)carve((size_t)B_*T_*512*4);
  float* ey_pre =(float*)carve((size_t)B_*U_*G_*4);
  float* hdec   =(float*)carve((size_t)B_*U_*512*4);
  float* lin_dec=(float*)carve((size_t)B_*U_*512*4);
  float* e_part =(float*)carve((size_t)8*8*256*4);
  float* attc   =(float*)carve(4096*4);
  float* states =(float*)carve(3*4096*4);
  unsigned* barcnt=(unsigned*)carve(1024);
  float* h0g=states;            // 4096
  float* h1g=states+4096;       // 2 x 4096 (ping-pong)

  hipMemsetAsync(states,0,3*4096*4,stream);
  hipMemsetAsync(barcnt,0,1024,stream);

  int n1=B_*T_*D_, n2=G_*512;
  k_f2bf    <<<(n1+255)/256,256,0,stream>>>(hs_pad,hs_bf,n1);
  k_trans_bf<<<(512*512+255)/256,256,0,stream>>>(W_att_dec,WdT,512,512);
  k_wi0a    <<<(n2+255)/256,256,0,stream>>>(W_ih0,Wi0a);
  k_f2bf    <<<(n2+255)/256,256,0,stream>>>(W_hh0,Whh0b,n2);
  k_f2bf    <<<(n2+255)/256,256,0,stream>>>(W_ih1,Wih1b,n2);
  k_f2bf    <<<(n2+255)/256,256,0,stream>>>(W_hh1,Whh1b,n2);
  k_woT     <<<(512*512+255)/256,256,0,stream>>>(W_out,WoT);

  // pre GEMMs
  k_gemm<<<dim3(32,8),256,0,stream>>>(hs_pad,nullptr,512, W_att_enc,512,0, b_att_enc,nullptr, 1,1, pe_bf,512, 512);
  k_peT <<<(B_*512*T_+255)/256,256,0,stream>>>(pe_bf,peT);
  k_gemm<<<dim3(32,8),256,0,stream>>>(hs_pad,nullptr,512, W_lin_enc,512,0, b_lin_enc,nullptr, 0,0, lin_enc,512, 512);
  k_gemm<<<dim3(8,32),256,0,stream>>>(emb,ys,512,        W_ih0,1024,1,    b_ih0,b_hh0,      0,0, ey_pre,2048, 512);

  // persistent scan: one launch for all 64 steps
  k_scan<<<NBLK,256,0,stream>>>(WdT,b_att_dec,peT,hs_bf,hlens,
                                Wi0a,Whh0b,Wih1b,Whh1b,b_ih1,b_hh1,ey_pre,
                                e_part,attc,h0g,h1g,hdec,barcnt);

  // post GEMM + joint
  k_gemm <<<dim3(8,8),256,0,stream>>>(hdec,nullptr,512, W_lin_dec,512,0, nullptr,nullptr, 0,0, lin_dec,512, 512);
  k_joint<<<4096,256,0,stream>>>(lin_enc,lin_dec,WoT,b_out,out);
}

// Round 10
// 1857.270 us; speedup vs baseline: 4.2545x; 1.1718x over previous
//
#include <hip/hip_runtime.h>
#include <cstddef>
#include <cstdint>

typedef unsigned short u16;
typedef __attribute__((ext_vector_type(8))) unsigned short u16x8;
typedef __attribute__((ext_vector_type(8))) short s16x8;
typedef __attribute__((ext_vector_type(4))) float f32x4;

#define B_ 8
#define T_ 256
#define U_ 64
#define D_ 512
#define G_ 2048   // 4*DUNITS
#define OD 500
#define NBLK 192  // 128 LSTM + 64 attention blocks (<=256 -> co-resident)
#define NGRP 12   // barrier fan-in groups of 16

__device__ __forceinline__ float bf2f(u16 u){ unsigned v=((unsigned)u)<<16; return __builtin_bit_cast(float,v); }
__device__ __forceinline__ u16 f2bf(float f){ unsigned u=__builtin_bit_cast(unsigned,f); u += 0x7fffu + ((u>>16)&1u); return (u16)(u>>16); }
__device__ __forceinline__ float sigm(float x){ return 1.f/(1.f+expf(-x)); }
__device__ __forceinline__ float wredsum(float v){
  #pragma unroll
  for(int o=32;o;o>>=1) v += __shfl_xor(v,o);
  return v;
}
__device__ __forceinline__ float wredmax(float v){
  #pragma unroll
  for(int o=32;o;o>>=1) v = fmaxf(v,__shfl_xor(v,o));
  return v;
}

// coherent cross-block access (proven correct r5-r9).
__device__ __forceinline__ float gload(const float* p){
  return __hip_atomic_load(p, __ATOMIC_RELAXED, __HIP_MEMORY_SCOPE_AGENT);
}
__device__ __forceinline__ void gstore(float* p, float v){
  __hip_atomic_store(p, v, __ATOMIC_RELAXED, __HIP_MEMORY_SCOPE_AGENT);
}
// device-coherent 16B load (bypasses L1+L2 like the agent atomics, 4x wider).
// NOTE: no waitcnt inside -- caller batches loads then waits once (rule #18:
// follow the waitcnt with sched_barrier(0)).
__device__ __forceinline__ f32x4 gload4(const float* p){
  f32x4 r;
  asm volatile("global_load_dwordx4 %0, %1, off sc0 sc1" : "=v"(r) : "v"(p));
  return r;
}
#define GWAIT() do{ asm volatile("s_waitcnt vmcnt(0)":::"memory"); __builtin_amdgcn_sched_barrier(0); }while(0)

// leaderless two-level grid barrier: 12 arrival lines x 16 blocks; the 16th
// arrival of each group RMWs the root; everyone polls root only.
__device__ __forceinline__ void gridbar(unsigned* bar, int bid, unsigned gen){
  __syncthreads();
  if(threadIdx.x==0){
    asm volatile("s_waitcnt vmcnt(0)" ::: "memory");
    unsigned old=__hip_atomic_fetch_add(bar+((bid>>4)<<5),1u,__ATOMIC_RELAXED,__HIP_MEMORY_SCOPE_AGENT);
    if(old==16u*gen-1u)
      __hip_atomic_fetch_add(bar+(NGRP<<5),1u,__ATOMIC_RELAXED,__HIP_MEMORY_SCOPE_AGENT);
    while(__hip_atomic_load(bar+(NGRP<<5),__ATOMIC_RELAXED,__HIP_MEMORY_SCOPE_AGENT) < (unsigned)NGRP*gen)
      __builtin_amdgcn_s_sleep(16);
  }
  __syncthreads();
}

// ---------------- conversion kernels (one-time per call) ----------------
__global__ void k_f2bf(const float* __restrict__ s, u16* __restrict__ d, int n){
  int i=blockIdx.x*256+threadIdx.x; if(i<n) d[i]=f2bf(s[i]);
}
__global__ void k_trans_bf(const float* __restrict__ s, u16* __restrict__ d, int R, int C){
  int i=blockIdx.x*256+threadIdx.x; if(i>=R*C) return;
  int c=i/R, r=i-c*R; d[i]=f2bf(s[(size_t)r*C+c]);
}
__global__ void k_wi0a(const float* __restrict__ W, u16* __restrict__ d){
  int i=blockIdx.x*256+threadIdx.x; if(i>=G_*D_) return;
  int g=i>>9, e=i&511; d[i]=f2bf(W[(size_t)g*1024 + 512 + e]);
}
__global__ void k_woT(const float* __restrict__ W, u16* __restrict__ d){
  int i=blockIdx.x*256+threadIdx.x; if(i>=512*512) return;
  int o=i>>9, j=i&511; d[i] = (o<OD)? f2bf(W[(size_t)j*OD+o]) : (u16)0;
}
// peT[b][a][t] = pe_bf[b][t][a]  (coalesced-on-t layout for the e-phase)
__global__ void k_peT(const u16* __restrict__ s, u16* __restrict__ d){
  int i=blockIdx.x*256+threadIdx.x; if(i>=B_*512*T_) return;
  int t=i&255, a=(i>>8)&511, b=i>>17;
  d[i]=s[((size_t)(b*256+t))*512 + a];
}

// ---------------- generic bf16-MFMA GEMM (pre/post passes) ----------------
__global__ __launch_bounds__(256) void k_gemm(
  const float* __restrict__ A, const int* __restrict__ gidx, int lda,
  const float* __restrict__ Bm, int ldb, int bT,
  const float* __restrict__ bias1, const float* __restrict__ bias2,
  int actTanh, int outBf16, void* __restrict__ C, int ldc, int K)
{
  __shared__ __align__(16) u16 As[64][40];
  __shared__ __align__(16) u16 Bs[64][40];
  int tid=threadIdx.x;
  int m0=blockIdx.x*64, n0=blockIdx.y*64;
  int w=tid>>6, l=tid&63;
  f32x4 acc[4];
  #pragma unroll
  for(int nt=0;nt<4;++nt) acc[nt]=(f32x4){0.f,0.f,0.f,0.f};
  int arow=tid>>2, aseg=tid&3;
  int ar = gidx ? gidx[m0+arow] : (m0+arow);
  const float* Ap = A + (size_t)ar*lda + aseg*8;

  for(int kt=0;kt<K/32;++kt){
    const float* ap = Ap + kt*32;
    f32x4 a0=*(const f32x4*)ap, a1=*(const f32x4*)(ap+4);
    #pragma unroll
    for(int i=0;i<4;++i){ As[arow][aseg*8+i]=f2bf(a0[i]); As[arow][aseg*8+4+i]=f2bf(a1[i]); }
    if(bT){
      const float* bp = Bm + (size_t)(n0+arow)*ldb + kt*32 + aseg*8;
      f32x4 b0=*(const f32x4*)bp, b1=*(const f32x4*)(bp+4);
      #pragma unroll
      for(int i=0;i<4;++i){ Bs[arow][aseg*8+i]=f2bf(b0[i]); Bs[arow][aseg*8+4+i]=f2bf(b1[i]); }
    } else {
      int bk=tid>>3, bn=(tid&7)*8;
      const float* bp = Bm + (size_t)(kt*32+bk)*ldb + n0 + bn;
      f32x4 b0=*(const f32x4*)bp, b1=*(const f32x4*)(bp+4);
      #pragma unroll
      for(int i=0;i<4;++i){ Bs[bn+i][bk]=f2bf(b0[i]); Bs[bn+4+i][bk]=f2bf(b1[i]); }
    }
    __syncthreads();
    s16x8 af = *(const s16x8*)&As[w*16 + (l&15)][(l>>4)*8];
    #pragma unroll
    for(int nt=0;nt<4;++nt){
      s16x8 bf = *(const s16x8*)&Bs[nt*16 + (l&15)][(l>>4)*8];
      acc[nt]=__builtin_amdgcn_mfma_f32_16x16x32_bf16(af,bf,acc[nt],0,0,0);
    }
    __syncthreads();
  }
  int mr = w*16 + ((l>>4)<<2), cc = l&15;
  #pragma unroll
  for(int nt=0;nt<4;++nt){
    int gn = n0 + nt*16 + cc;
    float bb = (bias1?bias1[gn]:0.f) + (bias2?bias2[gn]:0.f);
    #pragma unroll
    for(int r=0;r<4;++r){
      int gm = m0 + mr + r;
      float v = acc[nt][r] + bb;
      if(actTanh) v = tanhf(v);
      if(outBf16) ((u16*)C)[(size_t)gm*ldc+gn] = f2bf(v);
      else        ((float*)C)[(size_t)gm*ldc+gn] = v;
    }
  }
}

// one 16(rows)x16(batch)xK matvec unit on MFMA (weights L2-hot, x-panel in LDS)
__device__ __forceinline__ f32x4 mfma_unit(const u16* __restrict__ Wb, const u16* xb,
                                           int lb, int l, int k0, int nks){
  int rl=l&15;
  int row = ((rl>>2)<<9) + (lb<<2) + (rl&3);
  const u16* wp = Wb + (size_t)row*512 + k0 + ((l>>4)*8);
  const u16* xp = xb + (size_t)rl*520 + k0 + ((l>>4)*8);
  f32x4 acc=(f32x4){0.f,0.f,0.f,0.f};
  for(int ks=0;ks<nks;++ks){
    s16x8 af=*(const s16x8*)(wp + ks*32);
    s16x8 bf=*(const s16x8*)(xp + ks*32);
    acc=__builtin_amdgcn_mfma_f32_16x16x32_bf16(af,bf,acc,0,0,0);
  }
  return acc;
}

// stage 4096 coherent floats -> bf16 LDS panel [8][520] (+zero cols 8..15),
// 16 elements/thread via 4x dwordx4, one waitcnt.
__device__ __forceinline__ void stage_panel(const float* src, u16* dst, int tid){
  int base=tid*16;
  const float* p=src+base;
  f32x4 v0=gload4(p), v1=gload4(p+4), v2=gload4(p+8), v3=gload4(p+12);
  GWAIT();
  int bb=tid>>5, kk=base&511;
  u16* d=dst+bb*520+kk;
  u16x8 w0,w1;
  #pragma unroll
  for(int i=0;i<4;++i){ w0[i]=f2bf(v0[i]); w0[4+i]=f2bf(v1[i]); w1[i]=f2bf(v2[i]); w1[4+i]=f2bf(v3[i]); }
  *(u16x8*)d=w0; *(u16x8*)(d+8)=w1;
}
__device__ __forceinline__ void stage_panel2(const float* s0, u16* d0,
                                             const float* s1, u16* d1, int tid){
  int base=tid*16;
  const float* pa=s0+base; const float* pb=s1+base;
  f32x4 a0=gload4(pa), a1=gload4(pa+4), a2=gload4(pa+8), a3=gload4(pa+12);
  f32x4 b0=gload4(pb), b1=gload4(pb+4), b2=gload4(pb+8), b3=gload4(pb+12);
  GWAIT();
  int bb=tid>>5, kk=base&511;
  u16* dx=d0+bb*520+kk; u16* dh=d1+bb*520+kk;
  u16x8 w0,w1,w2,w3;
  #pragma unroll
  for(int i=0;i<4;++i){
    w0[i]=f2bf(a0[i]); w0[4+i]=f2bf(a1[i]); w1[i]=f2bf(a2[i]); w1[4+i]=f2bf(a3[i]);
    w2[i]=f2bf(b0[i]); w2[4+i]=f2bf(b1[i]); w3[i]=f2bf(b2[i]); w3[4+i]=f2bf(b3[i]);
  }
  *(u16x8*)dx=w0; *(u16x8*)(dx+8)=w1;
  *(u16x8*)dh=w2; *(u16x8*)(dh+8)=w3;
}

// ---------------- persistent scan kernel ----------------
// 192 blocks x 256 thr, 3 grid barriers/step:
//  X: LSTM blocks 0..127: LSTM1(u-1)+Whh0 on MFMA | attn blocks 128..191
//     (b, a-chunk): q-chunk + e-partials
//  Y: attn blocks (b, d-chunk): combine e-partials, exact softmax, attc
//  Z: LSTM blocks: LSTM0 on MFMA from attc
__global__ __launch_bounds__(256) void k_scan(
  const u16* __restrict__ WdT, const float* __restrict__ b_att_dec,
  const u16* __restrict__ peT, const u16* __restrict__ hs_bf, const int* __restrict__ hlens,
  const u16* __restrict__ Wi0a, const u16* __restrict__ Whh0b,
  const u16* __restrict__ Wih1b, const u16* __restrict__ Whh1b,
  const float* __restrict__ b_ih1, const float* __restrict__ b_hh1,
  const float* __restrict__ ey_pre, float* __restrict__ e_part,
  float* __restrict__ attc, float* __restrict__ h0g, float* __restrict__ h1g,
  float* __restrict__ hdec, unsigned* __restrict__ barcnt)
{
  __shared__ __align__(16) char smraw[38400];
  int tid=threadIdx.x, bid=blockIdx.x;
  unsigned baridx=0;

  if(bid<128){
    int lb=bid, w=tid>>6, l=tid&63;
    u16*  xbf=(u16*)smraw;              // 16x520 bf16 x-panel (h0 / attc)
    u16*  hbf=(u16*)(smraw+16640);      // 16x520 bf16 h1prev
    float* gl=(float*)(smraw+33280);    // [4][16][16] C-frag dump
    float* gp=(float*)(smraw+37376);    // [16][16] Whh0 partial, survives barriers
    for(int i=tid;i<16*520;i+=256){ xbf[i]=0; hbf[i]=0; }  // cols 8..15 stay 0
    float c0r=0.f, c1r=0.f;
    int jj=(tid>>3)&3, b=tid&7;         // epilogue cell for tid<32

    for(int u=0;u<=U_;++u){
      float* h1prev=h1g+(u&1)*4096;
      float* h1new =h1g+((u+1)&1)*4096;
      // ---- X ----
      stage_panel2(h0g,xbf,h1prev,hbf,tid);
      __syncthreads();
      f32x4 acc;
      if(w==0)      acc=mfma_unit(Wih1b,xbf,lb,l,0,16);
      else if(w==1) acc=mfma_unit(Whh1b,hbf,lb,l,0,16);
      else if(w==2) acc=mfma_unit(Whh0b,xbf,lb,l,0,8);
      else          acc=mfma_unit(Whh0b,xbf,lb,l,256,8);
      {
        float* gld=gl+w*256;
        #pragma unroll
        for(int r=0;r<4;++r) gld[((l>>4)*4+r)*16+(l&15)]=acc[r];
      }
      __syncthreads();
      gp[tid]=gl[512+tid]+gl[768+tid];      // Whh0 k-halves combined
      if(u>0 && tid<32){
        int j=lb*4+jj;
        float gv[4];
        #pragma unroll
        for(int g=0;g<4;++g){
          int ridx=g*4+jj, row=g*512+j;
          gv[g]=gl[ridx*16+b]+gl[256+ridx*16+b]+b_ih1[row]+b_hh1[row];
        }
        float i_=sigm(gv[0]), f_=sigm(gv[1]), g_=tanhf(gv[2]), o_=sigm(gv[3]);
        c1r=f_*c1r+i_*g_;
        float h=o_*tanhf(c1r);
        gstore(h1new+b*512+j,h);
        hdec[((size_t)(b*64+(u-1)))*512+j]=h;
      }
      if(u==U_) break;
      gridbar(barcnt,bid,++baridx);   // X -> Y
      gridbar(barcnt,bid,++baridx);   // Y -> Z (LSTM idle in Y)
      // ---- Z: LSTM0 = ey + gpart + Wi0a*attc ----
      stage_panel(attc,xbf,tid);
      __syncthreads();
      acc=mfma_unit(Wi0a,xbf,lb,l,w*128,4);
      {
        float* gld=gl+w*256;
        #pragma unroll
        for(int r=0;r<4;++r) gld[((l>>4)*4+r)*16+(l&15)]=acc[r];
      }
      __syncthreads();
      if(tid<32){
        int j=lb*4+jj;
        float gv[4];
        #pragma unroll
        for(int g=0;g<4;++g){
          int ridx=g*4+jj, row=g*512+j;
          gv[g]=gl[ridx*16+b]+gl[256+ridx*16+b]+gl[512+ridx*16+b]+gl[768+ridx*16+b]
               +gp[ridx*16+b]+ey_pre[((size_t)((b<<6)|u))*2048+row];
        }
        float i_=sigm(gv[0]), f_=sigm(gv[1]), g_=tanhf(gv[2]), o_=sigm(gv[3]);
        c0r=f_*c0r+i_*g_;
        gstore(h0g+b*512+j,o_*tanhf(c0r));
      }
      gridbar(barcnt,bid,++baridx);   // Z -> next X
    }
  } else {
    // ---- attention block: batch b, chunk c (a-chunk in X, d-chunk in Y) ----
    int k=bid-128, b=k>>3, c=k&7;
    float* h0s  =(float*)smraw;          // 512
    float* qpart=(float*)(smraw+2048);   // 256
    float* qs   =(float*)(smraw+3072);   // 64
    float* ew   =(float*)(smraw+3328);   // 256
    float* red  =(float*)(smraw+4352);   // 16
    float* apart=(float*)(smraw+4416);   // 256
    int wv=tid>>6, ln=tid&63;
    int hl=hlens[b];
    for(int u=0;u<=U_;++u){
      if(u<U_){
        // ---- X: q-chunk (64 a's, K split 4-way) + e-partials ----
        if(tid<128){
          f32x4 v=gload4(h0g+b*512+tid*4);
          GWAIT();
          *(f32x4*)(h0s+tid*4)=v;
        }
        __syncthreads();
        {
          int al=tid&63, ks=tid>>6;
          const u16* wr=WdT+(size_t)(c*64+al)*512 + ks*128;
          const float* xr=h0s+ks*128;
          float p0=0.f,p1=0.f,p2=0.f,p3=0.f;
          for(int kc=0;kc<16;++kc){
            u16x8 v=*(const u16x8*)(wr+kc*8);
            f32x4 xa=*(const f32x4*)(xr+kc*8), xb2=*(const f32x4*)(xr+kc*8+4);
            p0+=bf2f(v[0])*xa[0]+bf2f(v[2])*xa[2];
            p1+=bf2f(v[1])*xa[1]+bf2f(v[3])*xa[3];
            p2+=bf2f(v[4])*xb2[0]+bf2f(v[6])*xb2[2];
            p3+=bf2f(v[5])*xb2[1]+bf2f(v[7])*xb2[3];
          }
          qpart[(tid>>6)*64+al]=(p0+p1)+(p2+p3);
        }
        __syncthreads();
        if(tid<64) qs[tid]=tanhf(qpart[tid]+qpart[64+tid]+qpart[128+tid]+qpart[192+tid]
                                 +b_att_dec[c*64+tid]);
        __syncthreads();
        {
          // e_part[c][b][t=tid] over this block's 64 a's (lanes t-consecutive)
          const u16* pT=peT+(size_t)b*131072 + (size_t)(c*64)*256 + tid;
          float e0=0.f,e1=0.f,e2=0.f,e3=0.f;
          for(int j=0;j<64;j+=4){
            f32x4 q4=*(const f32x4*)(qs+j);
            e0+=q4[0]*bf2f(pT[(size_t)(j  )*256]);
            e1+=q4[1]*bf2f(pT[(size_t)(j+1)*256]);
            e2+=q4[2]*bf2f(pT[(size_t)(j+2)*256]);
            e3+=q4[3]*bf2f(pT[(size_t)(j+3)*256]);
          }
          gstore(e_part+(size_t)(c*8+b)*256+tid,(e0+e1)+(e2+e3));
        }
      }
      if(u==U_) break;
      gridbar(barcnt,bid,++baridx);   // X -> Y
      // ---- Y: combine e-partials, exact softmax, attc d-chunk ----
      {
        float ev=0.f;
        #pragma unroll
        for(int cc=0;cc<8;++cc) ev+=gload(e_part+(size_t)(cc*8+b)*256+tid);
        float val=(tid<hl)? ev : -1e30f;
        float m=wredmax(val);
        if(ln==0) red[wv]=m;
        __syncthreads();
        float M=fmaxf(fmaxf(red[0],red[1]),fmaxf(red[2],red[3]));
        float p=expf(val-M);
        float s=wredsum(p);
        if(ln==0) red[4+wv]=s;
        __syncthreads();
        float S=red[4]+red[5]+red[6]+red[7];
        ew[tid]=p;
        __syncthreads();
        int dl=tid&63, ts=tid>>6;
        const u16* hp=hs_bf+(size_t)b*131072 + (size_t)(ts*64)*512 + c*64 + dl;
        const float* ep=ew+ts*64;
        float a0=0.f,a1=0.f,a2=0.f,a3=0.f;
        for(int tt=0;tt<64;tt+=4){
          a0+=ep[tt  ]*bf2f(hp[(size_t)(tt  )*512]);
          a1+=ep[tt+1]*bf2f(hp[(size_t)(tt+1)*512]);
          a2+=ep[tt+2]*bf2f(hp[(size_t)(tt+2)*512]);
          a3+=ep[tt+3]*bf2f(hp[(size_t)(tt+3)*512]);
        }
        apart[ts*64+dl]=(a0+a1)+(a2+a3);
        __syncthreads();
        if(tid<64){
          float rS=1.f/S;
          gstore(attc+b*512+c*64+tid,
                 (apart[tid]+apart[64+tid]+apart[128+tid]+apart[192+tid])*rS);
        }
      }
      gridbar(barcnt,bid,++baridx);   // Y -> Z
      gridbar(barcnt,bid,++baridx);   // Z -> next X (attn idle in Z)
    }
  }
}

// ---------------- joint network ----------------
// 32-row t-tiles (33KB LDS -> 2 blocks/CU for latency hiding)
__global__ __launch_bounds__(256) void k_joint(
  const float* __restrict__ lin_enc, const float* __restrict__ lin_dec,
  const u16* __restrict__ WoT, const float* __restrict__ b_out,
  float* __restrict__ out)
{
  __shared__ __align__(16) u16 As[32*512];
  __shared__ float ld_s[512];
  int tid=threadIdx.x, bid=blockIdx.x;
  int b=bid>>9, u=(bid>>3)&63, t0=(bid&7)*32;
  for(int i=tid;i<512;i+=256) ld_s[i]=lin_dec[((size_t)((b<<6)|u))*512 + i];
  __syncthreads();
  const float* le = lin_enc + ((size_t)(b*256 + t0))*512;
  for(int it=0;it<8;++it){
    int idx=it*256+tid;
    int row=idx>>6, c0=(idx&63)*8;
    f32x4 x0=*(const f32x4*)(le + (size_t)row*512 + c0);
    f32x4 x1=*(const f32x4*)(le + (size_t)row*512 + c0 + 4);
    u16x8 pk;
    #pragma unroll
    for(int i=0;i<4;++i){
      pk[i]  =f2bf(tanhf(x0[i]+ld_s[c0+i]));
      pk[4+i]=f2bf(tanhf(x1[i]+ld_s[c0+4+i]));
    }
    int sc = c0 ^ ((row&7)<<3);
    *(u16x8*)&As[row*512+sc]=pk;
  }
  __syncthreads();
  int w=tid>>6, l=tid&63;
  for(int ch=0;ch<8;++ch){
    int n0=ch*64 + w*16;
    int o = n0 + (l&15);
    s16x8 bfr[16];
    const u16* wp = WoT + (size_t)o*512 + ((l>>4)*8);
    #pragma unroll
    for(int ks=0;ks<16;++ks) bfr[ks]=*(const s16x8*)(wp + ks*32);
    float bo = (o<OD)? b_out[o] : 0.f;
    #pragma unroll
    for(int mt=0;mt<2;++mt){
      f32x4 acc=(f32x4){0.f,0.f,0.f,0.f};
      int row = mt*16 + (l&15);
      int sw  = (row&7)<<3;
      #pragma unroll
      for(int ks=0;ks<16;++ks){
        int cidx=(ks*32 + (l>>4)*8) ^ sw;
        s16x8 af=*(const s16x8*)&As[row*512+cidx];
        acc=__builtin_amdgcn_mfma_f32_16x16x32_bf16(af,bfr[ks],acc,0,0,0);
      }
      if(o<OD){
        #pragma unroll
        for(int r=0;r<4;++r){
          int t = t0 + mt*16 + ((l>>4)<<2) + r;
          out[(((size_t)(b*256+t))*64 + u)*500 + o] = acc[r] + bo;
        }
      }
    }
  }
}

// ---------------- host launcher ----------------
extern "C" void kernel_launch(void* const* d_in, const int* in_sizes, int n_in,
                              void* d_out, int out_size, void* d_ws, size_t ws_size,
                              hipStream_t stream)
{
  (void)in_sizes; (void)n_in; (void)out_size; (void)ws_size;
  const float* hs_pad   =(const float*)d_in[0];
  const int*   ys       =(const int*)  d_in[1];
  const int*   hlens    =(const int*)  d_in[2];
  const float* emb      =(const float*)d_in[3];
  const float* W_ih0    =(const float*)d_in[4];
  const float* W_hh0    =(const float*)d_in[5];
  const float* b_ih0    =(const float*)d_in[6];
  const float* b_hh0    =(const float*)d_in[7];
  const float* W_ih1    =(const float*)d_in[8];
  const float* W_hh1    =(const float*)d_in[9];
  const float* b_ih1    =(const float*)d_in[10];
  const float* b_hh1    =(const float*)d_in[11];
  const float* W_att_enc=(const float*)d_in[12];
  const float* b_att_enc=(const float*)d_in[13];
  const float* W_att_dec=(const float*)d_in[14];
  const float* b_att_dec=(const float*)d_in[15];
  const float* W_lin_enc=(const float*)d_in[16];
  const float* b_lin_enc=(const float*)d_in[17];
  const float* W_lin_dec=(const float*)d_in[18];
  const float* W_out    =(const float*)d_in[19];
  const float* b_out    =(const float*)d_in[20];
  float* out=(float*)d_out;

  char* wp=(char*)d_ws;
  auto carve=[&](size_t bytes)->char*{ char* p=wp; wp += (bytes+255)&~(size_t)255; return p; };
  u16*   hs_bf  =(u16*)  carve((size_t)B_*T_*D_*2);
  u16*   pe_bf  =(u16*)  carve((size_t)B_*T_*D_*2);
  u16*   peT    =(u16*)  carve((size_t)B_*D_*T_*2);
  u16*   WdT    =(u16*)  carve((size_t)512*512*2);
  u16*   Wi0a   =(u16*)  carve((size_t)G_*512*2);
  u16*   Whh0b  =(u16*)  carve((size_t)G_*512*2);
  u16*   Wih1b  =(u16*)  carve((size_t)G_*512*2);
  u16*   Whh1b  =(u16*)  carve((size_t)G_*512*2);
  u16*   WoT    =(u16*)  carve((size_t)512*512*2);
  float* lin_enc=(float*)carve((size_t)B_*T_*512*4);
  float* ey_pre =(float*)carve((size_t)B_*U_*G_*4);
  float* hdec   =(float*)carve((size_t)B_*U_*512*4);
  float* lin_dec=(float*)carve((size_t)B_*U_*512*4);
  float* e_part =(float*)carve((size_t)8*8*256*4);
  float* attc   =(float*)carve(4096*4);
  float* states =(float*)carve(3*4096*4);
  unsigned* barcnt=(unsigned*)carve(2048);
  float* h0g=states;            // 4096
  float* h1g=states+4096;       // 2 x 4096 (ping-pong)

  hipMemsetAsync(states,0,3*4096*4,stream);
  hipMemsetAsync(barcnt,0,2048,stream);

  int n1=B_*T_*D_, n2=G_*512;
  k_f2bf    <<<(n1+255)/256,256,0,stream>>>(hs_pad,hs_bf,n1);
  k_trans_bf<<<(512*512+255)/256,256,0,stream>>>(W_att_dec,WdT,512,512);
  k_wi0a    <<<(n2+255)/256,256,0,stream>>>(W_ih0,Wi0a);
  k_f2bf    <<<(n2+255)/256,256,0,stream>>>(W_hh0,Whh0b,n2);
  k_f2bf    <<<(n2+255)/256,256,0,stream>>>(W_ih1,Wih1b,n2);
  k_f2bf    <<<(n2+255)/256,256,0,stream>>>(W_hh1,Whh1b,n2);
  k_woT     <<<(512*512+255)/256,256,0,stream>>>(W_out,WoT);

  // pre GEMMs
  k_gemm<<<dim3(32,8),256,0,stream>>>(hs_pad,nullptr,512, W_att_enc,512,0, b_att_enc,nullptr, 1,1, pe_bf,512, 512);
  k_peT <<<(B_*512*T_+255)/256,256,0,stream>>>(pe_bf,peT);
  k_gemm<<<dim3(32,8),256,0,stream>>>(hs_pad,nullptr,512, W_lin_enc,512,0, b_lin_enc,nullptr, 0,0, lin_enc,512, 512);
  k_gemm<<<dim3(8,32),256,0,stream>>>(emb,ys,512,        W_ih0,1024,1,    b_ih0,b_hh0,      0,0, ey_pre,2048, 512);

  // persistent scan: one launch for all 64 steps
  k_scan<<<NBLK,256,0,stream>>>(WdT,b_att_dec,peT,hs_bf,hlens,
                                Wi0a,Whh0b,Wih1b,Whh1b,b_ih1,b_hh1,ey_pre,
                                e_part,attc,h0g,h1g,hdec,barcnt);

  // post GEMM + joint
  k_gemm <<<dim3(8,8),256,0,stream>>>(hdec,nullptr,512, W_lin_dec,512,0, nullptr,nullptr, 0,0, lin_dec,512, 512);
  k_joint<<<4096,256,0,stream>>>(lin_enc,lin_dec,WoT,b_out,out);
}